// Round 1
// baseline (78410.138 us; speedup 1.0000x reference)
//
#include <hip/hip_runtime.h>
#include <hip/hip_bf16.h>

#define B_    256
#define S_    512
#define H_    256
#define TLEN_ 32
#define DI_   5
#define ENCSTRIDE 131072   // S_*H_

// ---------------------------------------------------------------------------
// init: zero state ping-pong buffers, barrier slots, set decoder inp0 = ones
// ---------------------------------------------------------------------------
__global__ __launch_bounds__(256) void init_kernel(float* H1, float* H2, float* C1,
                                                   float* C2, float* ZB, float* PRD,
                                                   unsigned* BAR) {
    int i = blockIdx.x * 256 + threadIdx.x;      // grid 512 -> 131072
    H1[i] = 0.f; H2[i] = 0.f;
    if (i < 65536) { C1[i] = 0.f; C2[i] = 0.f; ZB[i] = 0.f; }
    if (i < B_ * DI_) PRD[i] = 1.0f;
    if (i < 32) BAR[i] = 0u;
}

// ---------------------------------------------------------------------------
// pack a [1024][256] row-major weight into [k4][n] float4 layout:
// out[k4*1024 + n] = {w[n][4k4], w[n][4k4+1], w[n][4k4+2], w[n][4k4+3]}
// ---------------------------------------------------------------------------
__global__ __launch_bounds__(256) void pack_kernel(const float* __restrict__ m,
                                                   float4* __restrict__ out) {
    int idx = blockIdx.x * 256 + threadIdx.x;    // grid 256 -> 65536
    int k4 = idx >> 10, n = idx & 1023;
    out[idx] = ((const float4*)m)[n * 64 + k4];
}

// ---------------------------------------------------------------------------
// Weff[n][m] = sum_k wih_d1[n][k]*wdi[k][m]; beff[n] = b_d1[n] + wih_d1[n]·bdi
// ---------------------------------------------------------------------------
__global__ __launch_bounds__(256) void weff_kernel(const float* __restrict__ wih_d1,
                                                   const float* __restrict__ wdi,
                                                   const float* __restrict__ bdi,
                                                   const float* __restrict__ b_d1,
                                                   float* __restrict__ weff,
                                                   float* __restrict__ beff) {
    int n = blockIdx.x * 256 + threadIdx.x;      // grid 4 -> 1024
    float acc[DI_] = {0.f, 0.f, 0.f, 0.f, 0.f};
    float accb = 0.f;
    for (int k = 0; k < H_; k++) {
        float w = wih_d1[n * H_ + k];
        accb += w * bdi[k];
#pragma unroll
        for (int m = 0; m < DI_; m++) acc[m] += w * wdi[k * DI_ + m];
    }
#pragma unroll
    for (int m = 0; m < DI_; m++) weff[n * DI_ + m] = acc[m];
    beff[n] = b_d1[n] + accb;
}

// ---------------------------------------------------------------------------
// dot-chunk helper: a0..a3 += xv · w{0..3}
// ---------------------------------------------------------------------------
__device__ __forceinline__ void dot4(const float4 xv, const float4 w0, const float4 w1,
                                     const float4 w2, const float4 w3,
                                     float& a0, float& a1, float& a2, float& a3) {
    a0 += xv.x * w0.x + xv.y * w0.y + xv.z * w0.z + xv.w * w0.w;
    a1 += xv.x * w1.x + xv.y * w1.y + xv.z * w1.z + xv.w * w1.w;
    a2 += xv.x * w2.x + xv.y * w2.y + xv.z * w2.z + xv.w * w2.w;
    a3 += xv.x * w3.x + xv.y * w3.y + xv.z * w3.z + xv.w * w3.w;
}

__device__ __forceinline__ void lstm_epilogue(float a0, float a1, float a2, float a3,
                                              float cold, float& cn, float& hn) {
    float ii = 1.f / (1.f + expf(-a0));
    float ff = 1.f / (1.f + expf(-a1));
    float gg = tanhf(a2);
    float oo = 1.f / (1.f + expf(-a3));
    cn = ff * cold + ii * gg;
    hn = oo * tanhf(cn);
}

// ---------------------------------------------------------------------------
// 32-block barrier (one per 16-batch tile group). Agent-scope so correctness
// does not depend on XCD placement. gen monotonically increases; no sense flag.
// ---------------------------------------------------------------------------
__device__ __forceinline__ void tile_barrier(unsigned* cnt, unsigned* gen) {
    __syncthreads();
    if (threadIdx.x == 0) {
        __threadfence();   // release this block's h/c writes (agent scope)
        unsigned g = __hip_atomic_load(gen, __ATOMIC_RELAXED, __HIP_MEMORY_SCOPE_AGENT);
        unsigned arrived =
            __hip_atomic_fetch_add(cnt, 1u, __ATOMIC_ACQ_REL, __HIP_MEMORY_SCOPE_AGENT) + 1u;
        if (arrived == 32u) {
            __hip_atomic_store(cnt, 0u, __ATOMIC_RELAXED, __HIP_MEMORY_SCOPE_AGENT);
            __hip_atomic_fetch_add(gen, 1u, __ATOMIC_RELEASE, __HIP_MEMORY_SCOPE_AGENT);
        } else {
            while (__hip_atomic_load(gen, __ATOMIC_ACQUIRE, __HIP_MEMORY_SCOPE_AGENT) == g) {
                __builtin_amdgcn_s_sleep(1);
            }
        }
        __threadfence();   // acquire: invalidate stale L1/L2 before next step's reads
    }
    __syncthreads();
}

// ---------------------------------------------------------------------------
// Persistent fused encoder: ONE cooperative launch, 512 blocks x 256 threads.
// Block roles fixed for all 512 steps (pipelined: L2 runs one step behind L1).
// XCD-aware swizzle puts each 32-block group on one XCD (perf heuristic only).
// c-state lives in a register per thread for the whole sequence.
// ---------------------------------------------------------------------------
__global__ __launch_bounds__(256, 2) void enc_persistent_kernel(
    const float* __restrict__ srcs,
    const float* __restrict__ wih_e1,      // [1024][5] raw
    const float4* __restrict__ whh_e1p,    // packed [64][1024]
    const float4* __restrict__ wih_e2p,
    const float4* __restrict__ whh_e2p,
    const float* __restrict__ b_e1,
    const float* __restrict__ b_e2,
    float* __restrict__ H1,                // [2][65536] ping-pong
    float* __restrict__ H2,                // [2][65536] ping-pong
    float* __restrict__ C2,                // final c_enc for decoder carry
    __hip_bfloat16* __restrict__ encbf,    // [b][s][h]
    unsigned* __restrict__ bar_cnt,        // [16]
    unsigned* __restrict__ bar_gen)        // [16]
{
    __shared__ float sA[16][260];
    __shared__ float sB[16][260];
    int tid = threadIdx.x;

    // XCD-aware decomposition: bid%8 = XCD (round-robin heuristic).
    // Each group (batch-tile) = 32 blocks all with the same bid%8.
    int bid = blockIdx.x;                  // 0..511
    int x = bid & 7;
    int q = bid >> 3;                      // 0..63
    int grp = x + 8 * (q >> 5);            // batch-tile 0..15
    int rem = q & 31;
    bool isL2 = rem >= 16;
    int jt = rem & 15;
    int b0 = grp * 16, j0 = jt * 16;
    unsigned* cnt = bar_cnt + grp;
    unsigned* gen = bar_gen + grp;

    int bl = tid >> 4, jl = tid & 15, b = b0 + bl, j = j0 + jl;
    int idx = b * H_ + j;

    float creg = 0.f;                      // persistent cell state (register!)
    float bias0, bias1, bias2, bias3;
    float wx0[DI_], wx1[DI_], wx2[DI_], wx3[DI_];
    if (!isL2) {
        bias0 = b_e1[j]; bias1 = b_e1[256 + j]; bias2 = b_e1[512 + j]; bias3 = b_e1[768 + j];
#pragma unroll
        for (int k = 0; k < DI_; k++) {
            wx0[k] = wih_e1[j * DI_ + k];
            wx1[k] = wih_e1[(256 + j) * DI_ + k];
            wx2[k] = wih_e1[(512 + j) * DI_ + k];
            wx3[k] = wih_e1[(768 + j) * DI_ + k];
        }
    } else {
        bias0 = b_e2[j]; bias1 = b_e2[256 + j]; bias2 = b_e2[512 + j]; bias3 = b_e2[768 + j];
    }

    for (int t = 0; t <= S_; t++) {
        if (!isL2) {
            // -------- layer 1, step t --------
            if (t < S_) {
                if (tid < 16 * DI_) {
                    int r = tid / DI_, c = tid % DI_;
                    sA[r][c] = srcs[((long)(b0 + r) * S_ + t) * DI_ + c];
                }
                const float* hp = H1 + (((t & 1) ^ 1) << 16);
                for (int i = tid; i < 1024; i += 256) {
                    int r = i >> 6, c4 = i & 63;
                    ((float4*)&sB[r][0])[c4] = ((const float4*)(hp + (b0 + r) * H_))[c4];
                }
                __syncthreads();
                float a0 = bias0, a1 = bias1, a2 = bias2, a3 = bias3;
#pragma unroll
                for (int k = 0; k < DI_; k++) {
                    float xv = sA[bl][k];
                    a0 += xv * wx0[k]; a1 += xv * wx1[k];
                    a2 += xv * wx2[k]; a3 += xv * wx3[k];
                }
#pragma unroll 4
                for (int k4 = 0; k4 < 64; k4++) {
                    float4 xv = ((const float4*)&sB[bl][0])[k4];
                    dot4(xv, whh_e1p[(k4 << 10) + j], whh_e1p[(k4 << 10) + 256 + j],
                         whh_e1p[(k4 << 10) + 512 + j], whh_e1p[(k4 << 10) + 768 + j],
                         a0, a1, a2, a3);
                }
                float cn, hn;
                lstm_epilogue(a0, a1, a2, a3, creg, cn, hn);
                creg = cn;
                H1[((t & 1) << 16) + idx] = hn;
            }
        } else {
            // -------- layer 2, step u = t-1 --------
            if (t >= 1) {
                int u = t - 1;
                const float* xp = H1 + ((u & 1) << 16);          // e1[u] (prev iteration)
                const float* hp = H2 + (((u & 1) ^ 1) << 16);    // h2[u-1]
                for (int i = tid; i < 1024; i += 256) {
                    int r = i >> 6, c4 = i & 63;
                    ((float4*)&sA[r][0])[c4] = ((const float4*)(xp + (b0 + r) * H_))[c4];
                    ((float4*)&sB[r][0])[c4] = ((const float4*)(hp + (b0 + r) * H_))[c4];
                }
                __syncthreads();
                float a0 = bias0, a1 = bias1, a2 = bias2, a3 = bias3;
#pragma unroll 4
                for (int k4 = 0; k4 < 64; k4++) {
                    float4 xv = ((const float4*)&sA[bl][0])[k4];
                    dot4(xv, wih_e2p[(k4 << 10) + j], wih_e2p[(k4 << 10) + 256 + j],
                         wih_e2p[(k4 << 10) + 512 + j], wih_e2p[(k4 << 10) + 768 + j],
                         a0, a1, a2, a3);
                }
#pragma unroll 4
                for (int k4 = 0; k4 < 64; k4++) {
                    float4 xv = ((const float4*)&sB[bl][0])[k4];
                    dot4(xv, whh_e2p[(k4 << 10) + j], whh_e2p[(k4 << 10) + 256 + j],
                         whh_e2p[(k4 << 10) + 512 + j], whh_e2p[(k4 << 10) + 768 + j],
                         a0, a1, a2, a3);
                }
                float cn, hn;
                lstm_epilogue(a0, a1, a2, a3, creg, cn, hn);
                creg = cn;
                H2[((u & 1) << 16) + idx] = hn;
                encbf[(long)b * ENCSTRIDE + u * H_ + j] = __float2bfloat16(hn);
                if (u == S_ - 1) C2[idx] = cn;                   // decoder carry c
            }
        }
        if (t < S_) tile_barrier(cnt, gen);
    }
}

// ---------------------------------------------------------------------------
// Decoder LSTM cell, 16x16 tile, grid 256 x 256.
// kx==5: raw w5 [1024][5]; kx==256: packed wxp. use_whh: add hprev @ whh.
// ---------------------------------------------------------------------------
__global__ __launch_bounds__(256) void dec_cell_kernel(
    const float* __restrict__ x, int xstride,
    const float* __restrict__ w5,
    const float4* __restrict__ wxp, int kx,
    const float* __restrict__ hprev,
    const float4* __restrict__ whhp, int use_whh,
    const float* __restrict__ bias,
    const float* __restrict__ cprev,
    float* __restrict__ cout,
    float* __restrict__ hout)
{
    __shared__ float sA[16][260];
    __shared__ float sB[16][260];
    int tid = threadIdx.x;
    int b0 = ((int)blockIdx.x >> 4) * 16, j0 = ((int)blockIdx.x & 15) * 16;

    if (kx == DI_) {
        if (tid < 16 * DI_) {
            int r = tid / DI_, c = tid % DI_;
            sA[r][c] = x[(b0 + r) * xstride + c];
        }
    } else {
        for (int i = tid; i < 1024; i += 256) {
            int r = i >> 6, c4 = i & 63;
            ((float4*)&sA[r][0])[c4] = ((const float4*)(x + (long)(b0 + r) * xstride))[c4];
        }
    }
    if (use_whh) {
        for (int i = tid; i < 1024; i += 256) {
            int r = i >> 6, c4 = i & 63;
            ((float4*)&sB[r][0])[c4] = ((const float4*)(hprev + (long)(b0 + r) * H_))[c4];
        }
    }
    __syncthreads();

    int bl = tid >> 4, jl = tid & 15, b = b0 + bl, j = j0 + jl;
    float a0 = bias[j], a1 = bias[256 + j], a2 = bias[512 + j], a3 = bias[768 + j];

    if (kx == DI_) {
#pragma unroll
        for (int k = 0; k < DI_; k++) {
            float xv = sA[bl][k];
            a0 += xv * w5[j * DI_ + k];
            a1 += xv * w5[(256 + j) * DI_ + k];
            a2 += xv * w5[(512 + j) * DI_ + k];
            a3 += xv * w5[(768 + j) * DI_ + k];
        }
    } else {
#pragma unroll 4
        for (int k4 = 0; k4 < 64; k4++) {
            float4 xv = ((const float4*)&sA[bl][0])[k4];
            dot4(xv, wxp[(k4 << 10) + j], wxp[(k4 << 10) + 256 + j],
                 wxp[(k4 << 10) + 512 + j], wxp[(k4 << 10) + 768 + j], a0, a1, a2, a3);
        }
    }
    if (use_whh) {
#pragma unroll 4
        for (int k4 = 0; k4 < 64; k4++) {
            float4 xv = ((const float4*)&sB[bl][0])[k4];
            dot4(xv, whhp[(k4 << 10) + j], whhp[(k4 << 10) + 256 + j],
                 whhp[(k4 << 10) + 512 + j], whhp[(k4 << 10) + 768 + j], a0, a1, a2, a3);
        }
    }
    int idx = b * H_ + j;
    float cn, hn;
    lstm_epilogue(a0, a1, a2, a3, cprev[idx], cn, hn);
    cout[idx] = cn;
    hout[idx] = hn;
}

// ---------------------------------------------------------------------------
// energies[s][b] = dot(h2[b,:], enc[b,s,:])   grid 16384 (b x sblk8) x 256
// ---------------------------------------------------------------------------
__global__ __launch_bounds__(256) void energies_kernel(const float* __restrict__ h2,
                                                       const __hip_bfloat16* __restrict__ enc,
                                                       float* __restrict__ E) {
    __shared__ float lh[H_];
    __shared__ float red[4];
    int b = blockIdx.x >> 6;
    int s0 = (int)(blockIdx.x & 63) * 8;
    int tid = threadIdx.x;
    lh[tid] = h2[b * H_ + tid];
    __syncthreads();
    for (int si = 0; si < 8; si++) {
        int s = s0 + si;
        float p = lh[tid] * __bfloat162float(enc[(long)b * ENCSTRIDE + s * H_ + tid]);
#pragma unroll
        for (int off = 32; off > 0; off >>= 1) p += __shfl_down(p, off);
        if ((tid & 63) == 0) red[tid >> 6] = p;
        __syncthreads();
        if (tid == 0) E[s * B_ + b] = red[0] + red[1] + red[2] + red[3];
        __syncthreads();
    }
}

// ---------------------------------------------------------------------------
// softmax over batch (per s): W[s][b]      grid 512 x 256
// ---------------------------------------------------------------------------
__global__ __launch_bounds__(256) void softmax_kernel(const float* __restrict__ E,
                                                      float* __restrict__ W) {
    __shared__ float red[4];
    int s = blockIdx.x, tid = threadIdx.x;
    float v = E[s * B_ + tid];
    float m = v;
#pragma unroll
    for (int off = 32; off > 0; off >>= 1) m = fmaxf(m, __shfl_down(m, off));
    if ((tid & 63) == 0) red[tid >> 6] = m;
    __syncthreads();
    m = fmaxf(fmaxf(red[0], red[1]), fmaxf(red[2], red[3]));
    __syncthreads();
    float e = expf(v - m);
    float p = e;
#pragma unroll
    for (int off = 32; off > 0; off >>= 1) p += __shfl_down(p, off);
    if ((tid & 63) == 0) red[tid >> 6] = p;
    __syncthreads();
    float sum = red[0] + red[1] + red[2] + red[3];
    W[s * B_ + tid] = e / sum;
}

// ---------------------------------------------------------------------------
// context[b][h] = sum_s W[s][b]*enc[b,s,h]   grid 256 x 256
// ---------------------------------------------------------------------------
__global__ __launch_bounds__(256) void context_kernel(const float* __restrict__ W,
                                                      const __hip_bfloat16* __restrict__ enc,
                                                      float* __restrict__ out_ctx, // +t*H_ pre-offset
                                                      float* __restrict__ ctxc) {
    __shared__ float lw[S_];
    int b = blockIdx.x, tid = threadIdx.x;
    lw[tid] = W[tid * B_ + b];
    lw[256 + tid] = W[(256 + tid) * B_ + b];
    __syncthreads();
    float acc = 0.f;
    const __hip_bfloat16* ep = enc + (long)b * ENCSTRIDE + tid;
#pragma unroll 8
    for (int s = 0; s < S_; s++) acc += lw[s] * __bfloat162float(ep[s * H_]);
    out_ctx[(long)b * (TLEN_ * H_) + tid] = acc;
    ctxc[b * H_ + tid] = acc;
}

// ---------------------------------------------------------------------------
// cats = [h2|ctx]@ww.T + bw; pred = tanh(cats)@wop.T + bop   grid 256 x 64
// ---------------------------------------------------------------------------
__global__ __launch_bounds__(64) void decout_kernel(const float* __restrict__ h2,
                                                    const float* __restrict__ ctx,
                                                    const float* __restrict__ ww,
                                                    const float* __restrict__ bw,
                                                    const float* __restrict__ wop,
                                                    const float* __restrict__ bop,
                                                    float* __restrict__ out0,  // +t*DI_ pre-offset
                                                    float* __restrict__ pred) {
    int b = blockIdx.x, lane = threadIdx.x;
    float a[DI_] = {0.f, 0.f, 0.f, 0.f, 0.f};
    for (int k = lane; k < 2 * H_; k += 64) {
        float v = (k < H_) ? h2[b * H_ + k] : ctx[b * H_ + k - H_];
#pragma unroll
        for (int m = 0; m < DI_; m++) a[m] += v * ww[m * (2 * H_) + k];
    }
#pragma unroll
    for (int m = 0; m < DI_; m++)
        for (int off = 32; off > 0; off >>= 1) a[m] += __shfl_down(a[m], off);
    if (lane == 0) {
        float t5[DI_];
#pragma unroll
        for (int m = 0; m < DI_; m++) t5[m] = tanhf(a[m] + bw[m]);
#pragma unroll
        for (int m2 = 0; m2 < DI_; m2++) {
            float o = bop[m2];
#pragma unroll
            for (int m = 0; m < DI_; m++) o += t5[m] * wop[m2 * DI_ + m];
            out0[(long)b * (TLEN_ * DI_) + m2] = o;
            pred[b * DI_ + m2] = o;
        }
    }
}

// ---------------------------------------------------------------------------
extern "C" void kernel_launch(void* const* d_in, const int* in_sizes, int n_in,
                              void* d_out, int out_size, void* d_ws, size_t ws_size,
                              hipStream_t stream) {
    const float* srcs   = (const float*)d_in[0];
    const float* wih_e1 = (const float*)d_in[1];
    const float* whh_e1 = (const float*)d_in[2];
    const float* b_e1   = (const float*)d_in[3];
    const float* wih_e2 = (const float*)d_in[4];
    const float* whh_e2 = (const float*)d_in[5];
    const float* b_e2   = (const float*)d_in[6];
    const float* wdi    = (const float*)d_in[7];
    const float* bdi    = (const float*)d_in[8];
    const float* wih_d1 = (const float*)d_in[9];
    const float* whh_d1 = (const float*)d_in[10];
    const float* b_d1   = (const float*)d_in[11];
    const float* wih_d2 = (const float*)d_in[12];
    const float* whh_d2 = (const float*)d_in[13];
    const float* b_d2   = (const float*)d_in[14];
    const float* ww     = (const float*)d_in[15];
    const float* bw     = (const float*)d_in[16];
    const float* wop    = (const float*)d_in[17];
    const float* bop    = (const float*)d_in[18];

    float* ws = (float*)d_ws;
    __hip_bfloat16* ENCBF = (__hip_bfloat16*)d_ws;   // 33.5M bf16 = 16,777,216 float slots
    size_t o = 16777216;
    float4* PKE1 = (float4*)(ws + o); o += 262144;   // whh_e1 packed
    float4* PKX2 = (float4*)(ws + o); o += 262144;   // wih_e2 packed
    float4* PKH2 = (float4*)(ws + o); o += 262144;   // whh_e2 packed
    float4* PKD1 = (float4*)(ws + o); o += 262144;   // whh_d1 packed
    float4* PKD2 = (float4*)(ws + o); o += 262144;   // wih_d2 packed
    float* H1  = ws + o; o += 131072;                // [2][65536] ping-pong
    float* H2  = ws + o; o += 131072;                // [2][65536] ping-pong
    float* C1  = ws + o; o += 65536;
    float* C2  = ws + o; o += 65536;
    float* ZB  = ws + o; o += 65536;
    float* H1D = ws + o; o += 65536;
    float* C1D = ws + o; o += 65536;
    float* EN  = ws + o; o += 131072;
    float* WSM = ws + o; o += 131072;
    float* CTX = ws + o; o += 65536;
    float* PRD = ws + o; o += 1280;
    float* WEF = ws + o; o += 5120;
    float* BEF = ws + o; o += 1024;
    unsigned* BAR = (unsigned*)(ws + o); o += 32;    // [16] cnt + [16] gen
    unsigned* BARC = BAR;
    unsigned* BARG = BAR + 16;

    float* OUT0 = (float*)d_out;
    float* OUT1 = OUT0 + (size_t)B_ * TLEN_ * DI_;   // context_enc base

    dim3 t256(256);

    init_kernel<<<dim3(512), t256, 0, stream>>>(H1, H2, C1, C2, ZB, PRD, BAR);

    pack_kernel<<<dim3(256), t256, 0, stream>>>(whh_e1, PKE1);
    pack_kernel<<<dim3(256), t256, 0, stream>>>(wih_e2, PKX2);
    pack_kernel<<<dim3(256), t256, 0, stream>>>(whh_e2, PKH2);
    pack_kernel<<<dim3(256), t256, 0, stream>>>(whh_d1, PKD1);
    pack_kernel<<<dim3(256), t256, 0, stream>>>(wih_d2, PKD2);
    weff_kernel<<<dim3(4), t256, 0, stream>>>(wih_d1, wdi, bdi, b_d1, WEF, BEF);

    // ---------------- encoder: ONE persistent cooperative launch ----------------
    {
        void* kargs[] = {
            (void*)&srcs, (void*)&wih_e1, (void*)&PKE1, (void*)&PKX2, (void*)&PKH2,
            (void*)&b_e1, (void*)&b_e2, (void*)&H1, (void*)&H2, (void*)&C2,
            (void*)&ENCBF, (void*)&BARC, (void*)&BARG
        };
        hipLaunchCooperativeKernel((const void*)enc_persistent_kernel,
                                   dim3(512), dim3(256), kargs, 0, stream);
    }
    // final states: h_enc = H2 slot (511&1)=1, c_enc = C2
    float* H2F = H2 + 65536;

    // ---------------- decoder: 32 steps ----------------
    for (int t = 0; t < TLEN_; t++) {
        // layer 1: x = pred (K=5 via Weff), h = carry h2, c = carry c2
        dec_cell_kernel<<<dim3(256), t256, 0, stream>>>(
            PRD, DI_, WEF, nullptr, DI_,
            H2F, PKD1, 1, BEF, C2, C1D, H1D);
        // layer 2: x = h1d (K=256), h=c=0; writes new carry (h2 -> H2F, c2 -> C2)
        dec_cell_kernel<<<dim3(256), t256, 0, stream>>>(
            H1D, H_, nullptr, PKD2, H_,
            ZB, nullptr, 0, b_d2, ZB, C2, H2F);
        energies_kernel<<<dim3(16384), t256, 0, stream>>>(H2F, ENCBF, EN);
        softmax_kernel<<<dim3(512), t256, 0, stream>>>(EN, WSM);
        context_kernel<<<dim3(256), t256, 0, stream>>>(WSM, ENCBF, OUT1 + (size_t)t * H_, CTX);
        decout_kernel<<<dim3(256), dim3(64), 0, stream>>>(H2F, CTX, ww, bw, wop, bop,
                                                          OUT0 + (size_t)t * DI_, PRD);
    }
}

// Round 2
// 34757.022 us; speedup vs baseline: 2.2560x; 2.2560x over previous
//
#include <hip/hip_runtime.h>
#include <hip/hip_bf16.h>

#define B_    256
#define S_    512
#define H_    256
#define TLEN_ 32
#define DI_   5
#define ENCSTRIDE 131072   // S_*H_
#define CHUNK 32
#define NCHUNK 16          // S_/CHUNK
#define H1GBUF 2097152     // CHUNK*B_*H_ floats per ping-pong buffer

// ---------------------------------------------------------------------------
// init: zero ZB, set decoder inp0 = ones
// ---------------------------------------------------------------------------
__global__ __launch_bounds__(256) void init_kernel(float* ZB, float* PRD) {
    int i = blockIdx.x * 256 + threadIdx.x;      // grid 256 -> 65536
    ZB[i] = 0.f;
    if (i < B_ * DI_) PRD[i] = 1.0f;
}

// ---------------------------------------------------------------------------
// pack a [1024][256] row-major weight into [k4][n] float4 layout:
// out[k4*1024 + n] = {w[n][4k4], w[n][4k4+1], w[n][4k4+2], w[n][4k4+3]}
// ---------------------------------------------------------------------------
__global__ __launch_bounds__(256) void pack_kernel(const float* __restrict__ m,
                                                   float4* __restrict__ out) {
    int idx = blockIdx.x * 256 + threadIdx.x;    // grid 256 -> 65536
    int k4 = idx >> 10, n = idx & 1023;
    out[idx] = ((const float4*)m)[n * 64 + k4];
}

// ---------------------------------------------------------------------------
// Weff[n][m] = sum_k wih_d1[n][k]*wdi[k][m]; beff[n] = b_d1[n] + wih_d1[n]·bdi
// ---------------------------------------------------------------------------
__global__ __launch_bounds__(256) void weff_kernel(const float* __restrict__ wih_d1,
                                                   const float* __restrict__ wdi,
                                                   const float* __restrict__ bdi,
                                                   const float* __restrict__ b_d1,
                                                   float* __restrict__ weff,
                                                   float* __restrict__ beff) {
    int n = blockIdx.x * 256 + threadIdx.x;      // grid 4 -> 1024
    float acc[DI_] = {0.f, 0.f, 0.f, 0.f, 0.f};
    float accb = 0.f;
    for (int k = 0; k < H_; k++) {
        float w = wih_d1[n * H_ + k];
        accb += w * bdi[k];
#pragma unroll
        for (int m = 0; m < DI_; m++) acc[m] += w * wdi[k * DI_ + m];
    }
#pragma unroll
    for (int m = 0; m < DI_; m++) weff[n * DI_ + m] = acc[m];
    beff[n] = b_d1[n] + accb;
}

// ---------------------------------------------------------------------------
// dot-chunk helper: a0..a3 += xv · w{0..3}
// ---------------------------------------------------------------------------
__device__ __forceinline__ void dot4(const float4 xv, const float4 w0, const float4 w1,
                                     const float4 w2, const float4 w3,
                                     float& a0, float& a1, float& a2, float& a3) {
    a0 += xv.x * w0.x + xv.y * w0.y + xv.z * w0.z + xv.w * w0.w;
    a1 += xv.x * w1.x + xv.y * w1.y + xv.z * w1.z + xv.w * w1.w;
    a2 += xv.x * w2.x + xv.y * w2.y + xv.z * w2.z + xv.w * w2.w;
    a3 += xv.x * w3.x + xv.y * w3.y + xv.z * w3.z + xv.w * w3.w;
}

__device__ __forceinline__ void lstm_epilogue(float a0, float a1, float a2, float a3,
                                              float cold, float& cn, float& hn) {
    float ii = 1.f / (1.f + expf(-a0));
    float ff = 1.f / (1.f + expf(-a1));
    float gg = tanhf(a2);
    float oo = 1.f / (1.f + expf(-a3));
    cn = ff * cold + ii * gg;
    hn = oo * tanhf(cn);
}

// ---------------------------------------------------------------------------
// Chunked encoder: 17 launches (ci = 0..16), 128 blocks x 256 threads.
// Blocks 0..63: layer-1, chunk ci (4 batches/block, all 256 j per thread=j,
//   h1 ping-ponged in LDS, c in regs, h1 per step -> global H1G[ci&1]).
// Blocks 64..127: layer-2, chunk ci-1 (reads H1G[(ci-1)&1] written by the
//   PREVIOUS launch -> no intra-launch cross-block dependency).
// All math fp32, identical gate order/epilogue to the verified baseline.
// ---------------------------------------------------------------------------
__global__ __launch_bounds__(256) void enc_chunk_kernel(
    int ci,
    const float* __restrict__ srcs,
    const float* __restrict__ wih_e1,      // [1024][5] raw
    const float4* __restrict__ whh_e1p,    // packed [64][1024]
    const float4* __restrict__ wih_e2p,
    const float4* __restrict__ whh_e2p,
    const float* __restrict__ b_e1,
    const float* __restrict__ b_e2,
    float* __restrict__ H1G,               // [2][CHUNK][B_][H_]
    float* __restrict__ C1C,               // [B_][H_] layer-1 c carry
    float* __restrict__ H2C,               // [B_][H_] layer-2 h carry (final = h_enc)
    float* __restrict__ C2C,               // [B_][H_] layer-2 c carry (final = c_enc)
    __hip_bfloat16* __restrict__ encbf)    // [b][s][h]
{
    __shared__ float sS[4][160];           // srcs chunk [b][t*5+k]
    __shared__ float hb1[2][4][260];       // layer-1 h ping-pong
    __shared__ float x1s[2][4][260];       // layer-2 staged h1[u] ping-pong
    __shared__ float hb2[2][4][260];       // layer-2 h ping-pong
    int tid = threadIdx.x;
    int j = tid;

    float* h1cur = H1G + (ci & 1) * H1GBUF;
    const float* h1prev = H1G + ((ci & 1) ^ 1) * H1GBUF;

    if (blockIdx.x < 64) {
        // ================= layer 1, chunk ci =================
        if (ci >= NCHUNK) return;
        int b0 = blockIdx.x * 4;
        int ts = ci * CHUNK;

        // stage srcs chunk: 4 batches x 160 contiguous floats each
        for (int idx = tid; idx < 640; idx += 256) {
            int r = idx / 160, off = idx - r * 160;
            sS[r][off] = srcs[((long)(b0 + r) * S_ + ts) * DI_ + off];
        }
        // stage h_prev (last step of previous chunk) and load carries
        const float* hsrc = h1prev + (CHUNK - 1) * 65536;
        float c[4];
#pragma unroll
        for (int bb = 0; bb < 4; bb++) {
            hb1[0][bb][j] = (ci == 0) ? 0.f : hsrc[(b0 + bb) * H_ + j];
            c[bb] = (ci == 0) ? 0.f : C1C[(b0 + bb) * H_ + j];
        }
        float bias0 = b_e1[j], bias1 = b_e1[256 + j], bias2 = b_e1[512 + j], bias3 = b_e1[768 + j];
        float wx0[DI_], wx1[DI_], wx2[DI_], wx3[DI_];
#pragma unroll
        for (int k = 0; k < DI_; k++) {
            wx0[k] = wih_e1[j * DI_ + k];
            wx1[k] = wih_e1[(256 + j) * DI_ + k];
            wx2[k] = wih_e1[(512 + j) * DI_ + k];
            wx3[k] = wih_e1[(768 + j) * DI_ + k];
        }

        for (int tt = 0; tt < CHUNK; tt++) {
            __syncthreads();
            int ping = tt & 1, pong = ping ^ 1;
            float A[4][4];
#pragma unroll
            for (int bb = 0; bb < 4; bb++) {
                A[bb][0] = bias0; A[bb][1] = bias1; A[bb][2] = bias2; A[bb][3] = bias3;
#pragma unroll
                for (int k = 0; k < DI_; k++) {
                    float xv = sS[bb][tt * DI_ + k];
                    A[bb][0] += xv * wx0[k]; A[bb][1] += xv * wx1[k];
                    A[bb][2] += xv * wx2[k]; A[bb][3] += xv * wx3[k];
                }
            }
#pragma unroll 4
            for (int k4 = 0; k4 < 64; k4++) {
                float4 w0 = whh_e1p[(k4 << 10) + j];
                float4 w1 = whh_e1p[(k4 << 10) + 256 + j];
                float4 w2 = whh_e1p[(k4 << 10) + 512 + j];
                float4 w3 = whh_e1p[(k4 << 10) + 768 + j];
#pragma unroll
                for (int bb = 0; bb < 4; bb++) {
                    float4 h4 = ((const float4*)&hb1[ping][bb][0])[k4];
                    dot4(h4, w0, w1, w2, w3, A[bb][0], A[bb][1], A[bb][2], A[bb][3]);
                }
            }
#pragma unroll
            for (int bb = 0; bb < 4; bb++) {
                float cn, hn;
                lstm_epilogue(A[bb][0], A[bb][1], A[bb][2], A[bb][3], c[bb], cn, hn);
                c[bb] = cn;
                hb1[pong][bb][j] = hn;
                h1cur[tt * 65536 + (b0 + bb) * H_ + j] = hn;
            }
        }
#pragma unroll
        for (int bb = 0; bb < 4; bb++) C1C[(b0 + bb) * H_ + j] = c[bb];
    } else {
        // ================= layer 2, chunk ci-1 =================
        if (ci < 1) return;
        int b0 = (blockIdx.x - 64) * 4;
        int us = (ci - 1) * CHUNK;

        float c[4], hcar[4];
#pragma unroll
        for (int bb = 0; bb < 4; bb++) {
            hb2[0][bb][j] = (ci == 1) ? 0.f : H2C[(b0 + bb) * H_ + j];
            c[bb] = (ci == 1) ? 0.f : C2C[(b0 + bb) * H_ + j];
        }
        float bias0 = b_e2[j], bias1 = b_e2[256 + j], bias2 = b_e2[512 + j], bias3 = b_e2[768 + j];

        for (int tt = 0; tt < CHUNK; tt++) {
            int ping = tt & 1, pong = ping ^ 1;
            // stage x1 = h1[u] (written by previous launch): 1024 floats
            {
                int r = tid >> 6, c4 = tid & 63;
                ((float4*)&x1s[ping][r][0])[c4] =
                    ((const float4*)(h1prev + tt * 65536 + (b0 + r) * H_))[c4];
            }
            __syncthreads();
            float A[4][4];
#pragma unroll
            for (int bb = 0; bb < 4; bb++) {
                A[bb][0] = bias0; A[bb][1] = bias1; A[bb][2] = bias2; A[bb][3] = bias3;
            }
#pragma unroll 4
            for (int k4 = 0; k4 < 64; k4++) {
                float4 w0 = wih_e2p[(k4 << 10) + j];
                float4 w1 = wih_e2p[(k4 << 10) + 256 + j];
                float4 w2 = wih_e2p[(k4 << 10) + 512 + j];
                float4 w3 = wih_e2p[(k4 << 10) + 768 + j];
#pragma unroll
                for (int bb = 0; bb < 4; bb++) {
                    float4 h4 = ((const float4*)&x1s[ping][bb][0])[k4];
                    dot4(h4, w0, w1, w2, w3, A[bb][0], A[bb][1], A[bb][2], A[bb][3]);
                }
            }
#pragma unroll 4
            for (int k4 = 0; k4 < 64; k4++) {
                float4 w0 = whh_e2p[(k4 << 10) + j];
                float4 w1 = whh_e2p[(k4 << 10) + 256 + j];
                float4 w2 = whh_e2p[(k4 << 10) + 512 + j];
                float4 w3 = whh_e2p[(k4 << 10) + 768 + j];
#pragma unroll
                for (int bb = 0; bb < 4; bb++) {
                    float4 h4 = ((const float4*)&hb2[ping][bb][0])[k4];
                    dot4(h4, w0, w1, w2, w3, A[bb][0], A[bb][1], A[bb][2], A[bb][3]);
                }
            }
            int u = us + tt;
#pragma unroll
            for (int bb = 0; bb < 4; bb++) {
                float cn, hn;
                lstm_epilogue(A[bb][0], A[bb][1], A[bb][2], A[bb][3], c[bb], cn, hn);
                c[bb] = cn;
                hcar[bb] = hn;
                hb2[pong][bb][j] = hn;
                encbf[(long)(b0 + bb) * ENCSTRIDE + u * H_ + j] = __float2bfloat16(hn);
            }
        }
        // carry out (at ci==16 this IS the final h_enc/c_enc for the decoder)
#pragma unroll
        for (int bb = 0; bb < 4; bb++) {
            H2C[(b0 + bb) * H_ + j] = hcar[bb];
            C2C[(b0 + bb) * H_ + j] = c[bb];
        }
    }
}

// ---------------------------------------------------------------------------
// Decoder LSTM cell, 16x16 tile, grid 256 x 256.
// kx==5: raw w5 [1024][5]; kx==256: packed wxp. use_whh: add hprev @ whh.
// ---------------------------------------------------------------------------
__global__ __launch_bounds__(256) void dec_cell_kernel(
    const float* __restrict__ x, int xstride,
    const float* __restrict__ w5,
    const float4* __restrict__ wxp, int kx,
    const float* __restrict__ hprev,
    const float4* __restrict__ whhp, int use_whh,
    const float* __restrict__ bias,
    const float* __restrict__ cprev,
    float* __restrict__ cout,
    float* __restrict__ hout)
{
    __shared__ float sA[16][260];
    __shared__ float sB[16][260];
    int tid = threadIdx.x;
    int b0 = ((int)blockIdx.x >> 4) * 16, j0 = ((int)blockIdx.x & 15) * 16;

    if (kx == DI_) {
        if (tid < 16 * DI_) {
            int r = tid / DI_, c = tid % DI_;
            sA[r][c] = x[(b0 + r) * xstride + c];
        }
    } else {
        for (int i = tid; i < 1024; i += 256) {
            int r = i >> 6, c4 = i & 63;
            ((float4*)&sA[r][0])[c4] = ((const float4*)(x + (long)(b0 + r) * xstride))[c4];
        }
    }
    if (use_whh) {
        for (int i = tid; i < 1024; i += 256) {
            int r = i >> 6, c4 = i & 63;
            ((float4*)&sB[r][0])[c4] = ((const float4*)(hprev + (long)(b0 + r) * H_))[c4];
        }
    }
    __syncthreads();

    int bl = tid >> 4, jl = tid & 15, b = b0 + bl, j = j0 + jl;
    float a0 = bias[j], a1 = bias[256 + j], a2 = bias[512 + j], a3 = bias[768 + j];

    if (kx == DI_) {
#pragma unroll
        for (int k = 0; k < DI_; k++) {
            float xv = sA[bl][k];
            a0 += xv * w5[j * DI_ + k];
            a1 += xv * w5[(256 + j) * DI_ + k];
            a2 += xv * w5[(512 + j) * DI_ + k];
            a3 += xv * w5[(768 + j) * DI_ + k];
        }
    } else {
#pragma unroll 4
        for (int k4 = 0; k4 < 64; k4++) {
            float4 xv = ((const float4*)&sA[bl][0])[k4];
            dot4(xv, wxp[(k4 << 10) + j], wxp[(k4 << 10) + 256 + j],
                 wxp[(k4 << 10) + 512 + j], wxp[(k4 << 10) + 768 + j], a0, a1, a2, a3);
        }
    }
    if (use_whh) {
#pragma unroll 4
        for (int k4 = 0; k4 < 64; k4++) {
            float4 xv = ((const float4*)&sB[bl][0])[k4];
            dot4(xv, whhp[(k4 << 10) + j], whhp[(k4 << 10) + 256 + j],
                 whhp[(k4 << 10) + 512 + j], whhp[(k4 << 10) + 768 + j], a0, a1, a2, a3);
        }
    }
    int idx = b * H_ + j;
    float cn, hn;
    lstm_epilogue(a0, a1, a2, a3, cprev[idx], cn, hn);
    cout[idx] = cn;
    hout[idx] = hn;
}

// ---------------------------------------------------------------------------
// energies[s][b] = dot(h2[b,:], enc[b,s,:])   grid 16384 (b x sblk8) x 256
// ---------------------------------------------------------------------------
__global__ __launch_bounds__(256) void energies_kernel(const float* __restrict__ h2,
                                                       const __hip_bfloat16* __restrict__ enc,
                                                       float* __restrict__ E) {
    __shared__ float lh[H_];
    __shared__ float red[4];
    int b = blockIdx.x >> 6;
    int s0 = (int)(blockIdx.x & 63) * 8;
    int tid = threadIdx.x;
    lh[tid] = h2[b * H_ + tid];
    __syncthreads();
    for (int si = 0; si < 8; si++) {
        int s = s0 + si;
        float p = lh[tid] * __bfloat162float(enc[(long)b * ENCSTRIDE + s * H_ + tid]);
#pragma unroll
        for (int off = 32; off > 0; off >>= 1) p += __shfl_down(p, off);
        if ((tid & 63) == 0) red[tid >> 6] = p;
        __syncthreads();
        if (tid == 0) E[s * B_ + b] = red[0] + red[1] + red[2] + red[3];
        __syncthreads();
    }
}

// ---------------------------------------------------------------------------
// softmax over batch (per s): W[s][b]      grid 512 x 256
// ---------------------------------------------------------------------------
__global__ __launch_bounds__(256) void softmax_kernel(const float* __restrict__ E,
                                                      float* __restrict__ W) {
    __shared__ float red[4];
    int s = blockIdx.x, tid = threadIdx.x;
    float v = E[s * B_ + tid];
    float m = v;
#pragma unroll
    for (int off = 32; off > 0; off >>= 1) m = fmaxf(m, __shfl_down(m, off));
    if ((tid & 63) == 0) red[tid >> 6] = m;
    __syncthreads();
    m = fmaxf(fmaxf(red[0], red[1]), fmaxf(red[2], red[3]));
    __syncthreads();
    float e = expf(v - m);
    float p = e;
#pragma unroll
    for (int off = 32; off > 0; off >>= 1) p += __shfl_down(p, off);
    if ((tid & 63) == 0) red[tid >> 6] = p;
    __syncthreads();
    float sum = red[0] + red[1] + red[2] + red[3];
    W[s * B_ + tid] = e / sum;
}

// ---------------------------------------------------------------------------
// context[b][h] = sum_s W[s][b]*enc[b,s,h]   grid 256 x 256
// ---------------------------------------------------------------------------
__global__ __launch_bounds__(256) void context_kernel(const float* __restrict__ W,
                                                      const __hip_bfloat16* __restrict__ enc,
                                                      float* __restrict__ out_ctx, // +t*H_ pre-offset
                                                      float* __restrict__ ctxc) {
    __shared__ float lw[S_];
    int b = blockIdx.x, tid = threadIdx.x;
    lw[tid] = W[tid * B_ + b];
    lw[256 + tid] = W[(256 + tid) * B_ + b];
    __syncthreads();
    float acc = 0.f;
    const __hip_bfloat16* ep = enc + (long)b * ENCSTRIDE + tid;
#pragma unroll 8
    for (int s = 0; s < S_; s++) acc += lw[s] * __bfloat162float(ep[s * H_]);
    out_ctx[(long)b * (TLEN_ * H_) + tid] = acc;
    ctxc[b * H_ + tid] = acc;
}

// ---------------------------------------------------------------------------
// cats = [h2|ctx]@ww.T + bw; pred = tanh(cats)@wop.T + bop   grid 256 x 64
// ---------------------------------------------------------------------------
__global__ __launch_bounds__(64) void decout_kernel(const float* __restrict__ h2,
                                                    const float* __restrict__ ctx,
                                                    const float* __restrict__ ww,
                                                    const float* __restrict__ bw,
                                                    const float* __restrict__ wop,
                                                    const float* __restrict__ bop,
                                                    float* __restrict__ out0,  // +t*DI_ pre-offset
                                                    float* __restrict__ pred) {
    int b = blockIdx.x, lane = threadIdx.x;
    float a[DI_] = {0.f, 0.f, 0.f, 0.f, 0.f};
    for (int k = lane; k < 2 * H_; k += 64) {
        float v = (k < H_) ? h2[b * H_ + k] : ctx[b * H_ + k - H_];
#pragma unroll
        for (int m = 0; m < DI_; m++) a[m] += v * ww[m * (2 * H_) + k];
    }
#pragma unroll
    for (int m = 0; m < DI_; m++)
        for (int off = 32; off > 0; off >>= 1) a[m] += __shfl_down(a[m], off);
    if (lane == 0) {
        float t5[DI_];
#pragma unroll
        for (int m = 0; m < DI_; m++) t5[m] = tanhf(a[m] + bw[m]);
#pragma unroll
        for (int m2 = 0; m2 < DI_; m2++) {
            float o = bop[m2];
#pragma unroll
            for (int m = 0; m < DI_; m++) o += t5[m] * wop[m2 * DI_ + m];
            out0[(long)b * (TLEN_ * DI_) + m2] = o;
            pred[b * DI_ + m2] = o;
        }
    }
}

// ---------------------------------------------------------------------------
extern "C" void kernel_launch(void* const* d_in, const int* in_sizes, int n_in,
                              void* d_out, int out_size, void* d_ws, size_t ws_size,
                              hipStream_t stream) {
    const float* srcs   = (const float*)d_in[0];
    const float* wih_e1 = (const float*)d_in[1];
    const float* whh_e1 = (const float*)d_in[2];
    const float* b_e1   = (const float*)d_in[3];
    const float* wih_e2 = (const float*)d_in[4];
    const float* whh_e2 = (const float*)d_in[5];
    const float* b_e2   = (const float*)d_in[6];
    const float* wdi    = (const float*)d_in[7];
    const float* bdi    = (const float*)d_in[8];
    const float* wih_d1 = (const float*)d_in[9];
    const float* whh_d1 = (const float*)d_in[10];
    const float* b_d1   = (const float*)d_in[11];
    const float* wih_d2 = (const float*)d_in[12];
    const float* whh_d2 = (const float*)d_in[13];
    const float* b_d2   = (const float*)d_in[14];
    const float* ww     = (const float*)d_in[15];
    const float* bw     = (const float*)d_in[16];
    const float* wop    = (const float*)d_in[17];
    const float* bop    = (const float*)d_in[18];

    float* ws = (float*)d_ws;
    __hip_bfloat16* ENCBF = (__hip_bfloat16*)d_ws;   // 33.5M bf16 = 16,777,216 float slots
    size_t o = 16777216;
    float4* PKE1 = (float4*)(ws + o); o += 262144;   // whh_e1 packed
    float4* PKX2 = (float4*)(ws + o); o += 262144;   // wih_e2 packed
    float4* PKH2 = (float4*)(ws + o); o += 262144;   // whh_e2 packed
    float4* PKD1 = (float4*)(ws + o); o += 262144;   // whh_d1 packed
    float4* PKD2 = (float4*)(ws + o); o += 262144;   // wih_d2 packed
    float* H1G = ws + o; o += 2 * H1GBUF;            // [2][CHUNK][B][H] h1 chunk ping-pong
    float* C1C = ws + o; o += 65536;                 // layer-1 c carry
    float* H2C = ws + o; o += 65536;                 // layer-2 h carry / decoder h
    float* C2C = ws + o; o += 65536;                 // layer-2 c carry / decoder c
    float* ZB  = ws + o; o += 65536;
    float* H1D = ws + o; o += 65536;
    float* C1D = ws + o; o += 65536;
    float* EN  = ws + o; o += 131072;
    float* WSM = ws + o; o += 131072;
    float* CTX = ws + o; o += 65536;
    float* PRD = ws + o; o += 1280;
    float* WEF = ws + o; o += 5120;
    float* BEF = ws + o; o += 1024;

    float* OUT0 = (float*)d_out;
    float* OUT1 = OUT0 + (size_t)B_ * TLEN_ * DI_;   // context_enc base

    dim3 t256(256);

    init_kernel<<<dim3(256), t256, 0, stream>>>(ZB, PRD);

    pack_kernel<<<dim3(256), t256, 0, stream>>>(whh_e1, PKE1);
    pack_kernel<<<dim3(256), t256, 0, stream>>>(wih_e2, PKX2);
    pack_kernel<<<dim3(256), t256, 0, stream>>>(whh_e2, PKH2);
    pack_kernel<<<dim3(256), t256, 0, stream>>>(whh_d1, PKD1);
    pack_kernel<<<dim3(256), t256, 0, stream>>>(wih_d2, PKD2);
    weff_kernel<<<dim3(4), t256, 0, stream>>>(wih_d1, wdi, bdi, b_d1, WEF, BEF);

    // ---------------- encoder: 17 chunked launches ----------------
    for (int ci = 0; ci <= NCHUNK; ci++) {
        enc_chunk_kernel<<<dim3(128), t256, 0, stream>>>(
            ci, srcs, wih_e1, PKE1, PKX2, PKH2, b_e1, b_e2,
            H1G, C1C, H2C, C2C, ENCBF);
    }
    // final states: h_enc = H2C, c_enc = C2C

    // ---------------- decoder: 32 steps ----------------
    for (int t = 0; t < TLEN_; t++) {
        // layer 1: x = pred (K=5 via Weff), h = carry h2, c = carry c2
        dec_cell_kernel<<<dim3(256), t256, 0, stream>>>(
            PRD, DI_, WEF, nullptr, DI_,
            H2C, PKD1, 1, BEF, C2C, C1D, H1D);
        // layer 2: x = h1d (K=256), h=c=0; writes new carry (h2 -> H2C, c2 -> C2C)
        dec_cell_kernel<<<dim3(256), t256, 0, stream>>>(
            H1D, H_, nullptr, PKD2, H_,
            ZB, nullptr, 0, b_d2, ZB, C2C, H2C);
        energies_kernel<<<dim3(16384), t256, 0, stream>>>(H2C, ENCBF, EN);
        softmax_kernel<<<dim3(512), t256, 0, stream>>>(EN, WSM);
        context_kernel<<<dim3(256), t256, 0, stream>>>(WSM, ENCBF, OUT1 + (size_t)t * H_, CTX);
        decout_kernel<<<dim3(256), dim3(64), 0, stream>>>(H2C, CTX, ww, bw, wop, bop,
                                                          OUT0 + (size_t)t * DI_, PRD);
    }
}

// Round 3
// 14915.327 us; speedup vs baseline: 5.2570x; 2.3303x over previous
//
#include <hip/hip_runtime.h>
#include <hip/hip_bf16.h>

#define B_    256
#define S_    512
#define H_    256
#define TLEN_ 32
#define DI_   5
#define ENCSTRIDE 131072   // S_*H_
#define CHUNK 32
#define NCHUNK 16          // S_/CHUNK
#define H1GBUF 2097152     // CHUNK*B_*H_ floats per ping-pong buffer
#define NB 4               // batches per encoder block

// ---------------------------------------------------------------------------
// init: zero ZB, set decoder inp0 = ones
// ---------------------------------------------------------------------------
__global__ __launch_bounds__(256) void init_kernel(float* ZB, float* PRD) {
    int i = blockIdx.x * 256 + threadIdx.x;      // grid 256 -> 65536
    ZB[i] = 0.f;
    if (i < B_ * DI_) PRD[i] = 1.0f;
}

// ---------------------------------------------------------------------------
// pack a [1024][256] row-major weight into [k4][n] float4 layout:
// out[k4*1024 + n] = {w[n][4k4], w[n][4k4+1], w[n][4k4+2], w[n][4k4+3]}
// ---------------------------------------------------------------------------
__global__ __launch_bounds__(256) void pack_kernel(const float* __restrict__ m,
                                                   float4* __restrict__ out) {
    int idx = blockIdx.x * 256 + threadIdx.x;    // grid 256 -> 65536
    int k4 = idx >> 10, n = idx & 1023;
    out[idx] = ((const float4*)m)[n * 64 + k4];
}

// ---------------------------------------------------------------------------
// Weff[n][m] = sum_k wih_d1[n][k]*wdi[k][m]; beff[n] = b_d1[n] + wih_d1[n]·bdi
// ---------------------------------------------------------------------------
__global__ __launch_bounds__(256) void weff_kernel(const float* __restrict__ wih_d1,
                                                   const float* __restrict__ wdi,
                                                   const float* __restrict__ bdi,
                                                   const float* __restrict__ b_d1,
                                                   float* __restrict__ weff,
                                                   float* __restrict__ beff) {
    int n = blockIdx.x * 256 + threadIdx.x;      // grid 4 -> 1024
    float acc[DI_] = {0.f, 0.f, 0.f, 0.f, 0.f};
    float accb = 0.f;
    for (int k = 0; k < H_; k++) {
        float w = wih_d1[n * H_ + k];
        accb += w * bdi[k];
#pragma unroll
        for (int m = 0; m < DI_; m++) acc[m] += w * wdi[k * DI_ + m];
    }
#pragma unroll
    for (int m = 0; m < DI_; m++) weff[n * DI_ + m] = acc[m];
    beff[n] = b_d1[n] + accb;
}

// ---------------------------------------------------------------------------
// dot-chunk helper: a0..a3 += xv · w{0..3}
// ---------------------------------------------------------------------------
__device__ __forceinline__ void dot4(const float4 xv, const float4 w0, const float4 w1,
                                     const float4 w2, const float4 w3,
                                     float& a0, float& a1, float& a2, float& a3) {
    a0 += xv.x * w0.x + xv.y * w0.y + xv.z * w0.z + xv.w * w0.w;
    a1 += xv.x * w1.x + xv.y * w1.y + xv.z * w1.z + xv.w * w1.w;
    a2 += xv.x * w2.x + xv.y * w2.y + xv.z * w2.z + xv.w * w2.w;
    a3 += xv.x * w3.x + xv.y * w3.y + xv.z * w3.z + xv.w * w3.w;
}

__device__ __forceinline__ void lstm_epilogue(float a0, float a1, float a2, float a3,
                                              float cold, float& cn, float& hn) {
    float ii = 1.f / (1.f + expf(-a0));
    float ff = 1.f / (1.f + expf(-a1));
    float gg = tanhf(a2);
    float oo = 1.f / (1.f + expf(-a3));
    cn = ff * cold + ii * gg;
    hn = oo * tanhf(cn);
}

// ---------------------------------------------------------------------------
// Chunked encoder v3: 17 launches (ci = 0..16), 128 blocks x 1024 threads.
// 16 waves/block -> 4 waves/SIMD for latency hiding (v2 had 1 wave/SIMD,
// VALUBusy 8%). Thread roles:
//   accumulate phase: (kh = tid>>8) owns K-slice [kh*64, kh*64+64), j = tid&255
//   reduce phase:     (bb = tid>>8) owns batch bb, j = tid&255; c in 1 register
// Partials cross kh via 64KB LDS (float4, contiguous b128, conflict-free).
// Blocks 0..63: layer-1 chunk ci; blocks 64..127: layer-2 chunk ci-1 (reads
// h1 written by the PREVIOUS launch -> no cross-block dependency).
// ---------------------------------------------------------------------------
__global__ __launch_bounds__(1024, 4) void enc_chunk_kernel(
    int ci,
    const float* __restrict__ srcs,
    const float* __restrict__ wih_e1,      // [1024][5] raw
    const float4* __restrict__ whh_e1p,    // packed [64][1024]
    const float4* __restrict__ wih_e2p,
    const float4* __restrict__ whh_e2p,
    const float* __restrict__ b_e1,
    const float* __restrict__ b_e2,
    float* __restrict__ H1G,               // [2][CHUNK][B_][H_]
    float* __restrict__ C1C,               // [B_][H_] layer-1 c carry
    float* __restrict__ H2C,               // [B_][H_] layer-2 h carry (final = h_enc)
    float* __restrict__ C2C,               // [B_][H_] layer-2 c carry (final = c_enc)
    __hip_bfloat16* __restrict__ encbf)    // [b][s][h]
{
    __shared__ float4 red[4][NB][256];     // [kh][bb][j] -> 4 gate partials, 64KB
    __shared__ float hb[NB][260];          // own-layer h (current step)
    __shared__ float xs[NB][260];          // L1: srcs chunk; L2: x1 slice

    int tid = threadIdx.x;
    int kh = tid >> 8;                     // K-slice (accum) == bb (reduce)
    int j  = tid & 255;
    int k40 = kh << 4;                     // 16 k4 iterations per slice

    float* h1cur = H1G + (ci & 1) * H1GBUF;
    const float* h1prev = H1G + ((ci & 1) ^ 1) * H1GBUF;

    if (blockIdx.x < 64) {
        // ================= layer 1, chunk ci =================
        if (ci >= NCHUNK) return;
        int b0 = blockIdx.x * NB;
        int ts = ci * CHUNK;

        // stage srcs chunk: NB batches x 160 contiguous floats each
        for (int idx = tid; idx < NB * CHUNK * DI_; idx += 1024) {
            int r = idx / (CHUNK * DI_), off = idx - r * (CHUNK * DI_);
            xs[r][off] = srcs[((long)(b0 + r) * S_ + ts) * DI_ + off];
        }
        // carries (reduce role: batch kh)
        {
            const float* hsrc = h1prev + (CHUNK - 1) * 65536;
            hb[kh][j] = (ci == 0) ? 0.f : hsrc[(b0 + kh) * H_ + j];
        }
        float creg = (ci == 0) ? 0.f : C1C[(b0 + kh) * H_ + j];
        float bias0 = b_e1[j], bias1 = b_e1[256 + j], bias2 = b_e1[512 + j], bias3 = b_e1[768 + j];
        float wx[4][DI_];
#pragma unroll
        for (int k = 0; k < DI_; k++) {
            wx[0][k] = wih_e1[j * DI_ + k];
            wx[1][k] = wih_e1[(256 + j) * DI_ + k];
            wx[2][k] = wih_e1[(512 + j) * DI_ + k];
            wx[3][k] = wih_e1[(768 + j) * DI_ + k];
        }

        for (int tt = 0; tt < CHUNK; tt++) {
            __syncthreads();               // hb/xs ready; prev red reads done
            float A[NB][4];
#pragma unroll
            for (int bb = 0; bb < NB; bb++) {
                A[bb][0] = 0.f; A[bb][1] = 0.f; A[bb][2] = 0.f; A[bb][3] = 0.f;
            }
            if (kh == 0) {                 // input projection K=5 (wave-uniform branch)
#pragma unroll
                for (int bb = 0; bb < NB; bb++)
#pragma unroll
                    for (int k = 0; k < DI_; k++) {
                        float xv = xs[bb][tt * DI_ + k];
                        A[bb][0] += xv * wx[0][k];
                        A[bb][1] += xv * wx[1][k];
                        A[bb][2] += xv * wx[2][k];
                        A[bb][3] += xv * wx[3][k];
                    }
            }
#pragma unroll 4
            for (int k4 = k40; k4 < k40 + 16; k4++) {
                float4 w0 = whh_e1p[(k4 << 10) + j];
                float4 w1 = whh_e1p[(k4 << 10) + 256 + j];
                float4 w2 = whh_e1p[(k4 << 10) + 512 + j];
                float4 w3 = whh_e1p[(k4 << 10) + 768 + j];
#pragma unroll
                for (int bb = 0; bb < NB; bb++) {
                    float4 h4 = ((const float4*)&hb[bb][0])[k4];
                    dot4(h4, w0, w1, w2, w3, A[bb][0], A[bb][1], A[bb][2], A[bb][3]);
                }
            }
#pragma unroll
            for (int bb = 0; bb < NB; bb++)
                red[kh][bb][j] = make_float4(A[bb][0], A[bb][1], A[bb][2], A[bb][3]);
            __syncthreads();               // red complete; hb/xs reads done
            float a0 = bias0, a1 = bias1, a2 = bias2, a3 = bias3;
#pragma unroll
            for (int kk = 0; kk < 4; kk++) {
                float4 v = red[kk][kh][j];
                a0 += v.x; a1 += v.y; a2 += v.z; a3 += v.w;
            }
            float cn, hn;
            lstm_epilogue(a0, a1, a2, a3, creg, cn, hn);
            creg = cn;
            hb[kh][j] = hn;
            h1cur[tt * 65536 + (b0 + kh) * H_ + j] = hn;
        }
        C1C[(b0 + kh) * H_ + j] = creg;
    } else {
        // ================= layer 2, chunk ci-1 =================
        if (ci < 1) return;
        int b0 = (blockIdx.x - 64) * NB;
        int us = (ci - 1) * CHUNK;

        hb[kh][j] = (ci == 1) ? 0.f : H2C[(b0 + kh) * H_ + j];
        float creg = (ci == 1) ? 0.f : C2C[(b0 + kh) * H_ + j];
        float hlast = 0.f;
        float bias0 = b_e2[j], bias1 = b_e2[256 + j], bias2 = b_e2[512 + j], bias3 = b_e2[768 + j];

        for (int tt = 0; tt < CHUNK; tt++) {
            // stage x1 = h1[u] slice written by the previous launch
            xs[kh][j] = h1prev[tt * 65536 + (b0 + kh) * H_ + j];
            __syncthreads();               // xs/hb ready; prev red reads done
            float A[NB][4];
#pragma unroll
            for (int bb = 0; bb < NB; bb++) {
                A[bb][0] = 0.f; A[bb][1] = 0.f; A[bb][2] = 0.f; A[bb][3] = 0.f;
            }
#pragma unroll 4
            for (int k4 = k40; k4 < k40 + 16; k4++) {
                float4 w0 = wih_e2p[(k4 << 10) + j];
                float4 w1 = wih_e2p[(k4 << 10) + 256 + j];
                float4 w2 = wih_e2p[(k4 << 10) + 512 + j];
                float4 w3 = wih_e2p[(k4 << 10) + 768 + j];
#pragma unroll
                for (int bb = 0; bb < NB; bb++) {
                    float4 x4 = ((const float4*)&xs[bb][0])[k4];
                    dot4(x4, w0, w1, w2, w3, A[bb][0], A[bb][1], A[bb][2], A[bb][3]);
                }
            }
#pragma unroll 4
            for (int k4 = k40; k4 < k40 + 16; k4++) {
                float4 w0 = whh_e2p[(k4 << 10) + j];
                float4 w1 = whh_e2p[(k4 << 10) + 256 + j];
                float4 w2 = whh_e2p[(k4 << 10) + 512 + j];
                float4 w3 = whh_e2p[(k4 << 10) + 768 + j];
#pragma unroll
                for (int bb = 0; bb < NB; bb++) {
                    float4 h4 = ((const float4*)&hb[bb][0])[k4];
                    dot4(h4, w0, w1, w2, w3, A[bb][0], A[bb][1], A[bb][2], A[bb][3]);
                }
            }
#pragma unroll
            for (int bb = 0; bb < NB; bb++)
                red[kh][bb][j] = make_float4(A[bb][0], A[bb][1], A[bb][2], A[bb][3]);
            __syncthreads();               // red complete; xs/hb reads done
            float a0 = bias0, a1 = bias1, a2 = bias2, a3 = bias3;
#pragma unroll
            for (int kk = 0; kk < 4; kk++) {
                float4 v = red[kk][kh][j];
                a0 += v.x; a1 += v.y; a2 += v.z; a3 += v.w;
            }
            float cn, hn;
            lstm_epilogue(a0, a1, a2, a3, creg, cn, hn);
            creg = cn;
            hlast = hn;
            hb[kh][j] = hn;
            encbf[(long)(b0 + kh) * ENCSTRIDE + (us + tt) * H_ + j] = __float2bfloat16(hn);
        }
        H2C[(b0 + kh) * H_ + j] = hlast;
        C2C[(b0 + kh) * H_ + j] = creg;
    }
}

// ---------------------------------------------------------------------------
// Decoder LSTM cell, 16x16 tile, grid 256 x 256.
// kx==5: raw w5 [1024][5]; kx==256: packed wxp. use_whh: add hprev @ whh.
// ---------------------------------------------------------------------------
__global__ __launch_bounds__(256) void dec_cell_kernel(
    const float* __restrict__ x, int xstride,
    const float* __restrict__ w5,
    const float4* __restrict__ wxp, int kx,
    const float* __restrict__ hprev,
    const float4* __restrict__ whhp, int use_whh,
    const float* __restrict__ bias,
    const float* __restrict__ cprev,
    float* __restrict__ cout,
    float* __restrict__ hout)
{
    __shared__ float sA[16][260];
    __shared__ float sB[16][260];
    int tid = threadIdx.x;
    int b0 = ((int)blockIdx.x >> 4) * 16, j0 = ((int)blockIdx.x & 15) * 16;

    if (kx == DI_) {
        if (tid < 16 * DI_) {
            int r = tid / DI_, c = tid % DI_;
            sA[r][c] = x[(b0 + r) * xstride + c];
        }
    } else {
        for (int i = tid; i < 1024; i += 256) {
            int r = i >> 6, c4 = i & 63;
            ((float4*)&sA[r][0])[c4] = ((const float4*)(x + (long)(b0 + r) * xstride))[c4];
        }
    }
    if (use_whh) {
        for (int i = tid; i < 1024; i += 256) {
            int r = i >> 6, c4 = i & 63;
            ((float4*)&sB[r][0])[c4] = ((const float4*)(hprev + (long)(b0 + r) * H_))[c4];
        }
    }
    __syncthreads();

    int bl = tid >> 4, jl = tid & 15, b = b0 + bl, j = j0 + jl;
    float a0 = bias[j], a1 = bias[256 + j], a2 = bias[512 + j], a3 = bias[768 + j];

    if (kx == DI_) {
#pragma unroll
        for (int k = 0; k < DI_; k++) {
            float xv = sA[bl][k];
            a0 += xv * w5[j * DI_ + k];
            a1 += xv * w5[(256 + j) * DI_ + k];
            a2 += xv * w5[(512 + j) * DI_ + k];
            a3 += xv * w5[(768 + j) * DI_ + k];
        }
    } else {
#pragma unroll 4
        for (int k4 = 0; k4 < 64; k4++) {
            float4 xv = ((const float4*)&sA[bl][0])[k4];
            dot4(xv, wxp[(k4 << 10) + j], wxp[(k4 << 10) + 256 + j],
                 wxp[(k4 << 10) + 512 + j], wxp[(k4 << 10) + 768 + j], a0, a1, a2, a3);
        }
    }
    if (use_whh) {
#pragma unroll 4
        for (int k4 = 0; k4 < 64; k4++) {
            float4 xv = ((const float4*)&sB[bl][0])[k4];
            dot4(xv, whhp[(k4 << 10) + j], whhp[(k4 << 10) + 256 + j],
                 whhp[(k4 << 10) + 512 + j], whhp[(k4 << 10) + 768 + j], a0, a1, a2, a3);
        }
    }
    int idx = b * H_ + j;
    float cn, hn;
    lstm_epilogue(a0, a1, a2, a3, cprev[idx], cn, hn);
    cout[idx] = cn;
    hout[idx] = hn;
}

// ---------------------------------------------------------------------------
// energies[s][b] = dot(h2[b,:], enc[b,s,:])   grid 16384 (b x sblk8) x 256
// ---------------------------------------------------------------------------
__global__ __launch_bounds__(256) void energies_kernel(const float* __restrict__ h2,
                                                       const __hip_bfloat16* __restrict__ enc,
                                                       float* __restrict__ E) {
    __shared__ float lh[H_];
    __shared__ float red[4];
    int b = blockIdx.x >> 6;
    int s0 = (int)(blockIdx.x & 63) * 8;
    int tid = threadIdx.x;
    lh[tid] = h2[b * H_ + tid];
    __syncthreads();
    for (int si = 0; si < 8; si++) {
        int s = s0 + si;
        float p = lh[tid] * __bfloat162float(enc[(long)b * ENCSTRIDE + s * H_ + tid]);
#pragma unroll
        for (int off = 32; off > 0; off >>= 1) p += __shfl_down(p, off);
        if ((tid & 63) == 0) red[tid >> 6] = p;
        __syncthreads();
        if (tid == 0) E[s * B_ + b] = red[0] + red[1] + red[2] + red[3];
        __syncthreads();
    }
}

// ---------------------------------------------------------------------------
// softmax over batch (per s): W[s][b]      grid 512 x 256
// ---------------------------------------------------------------------------
__global__ __launch_bounds__(256) void softmax_kernel(const float* __restrict__ E,
                                                      float* __restrict__ W) {
    __shared__ float red[4];
    int s = blockIdx.x, tid = threadIdx.x;
    float v = E[s * B_ + tid];
    float m = v;
#pragma unroll
    for (int off = 32; off > 0; off >>= 1) m = fmaxf(m, __shfl_down(m, off));
    if ((tid & 63) == 0) red[tid >> 6] = m;
    __syncthreads();
    m = fmaxf(fmaxf(red[0], red[1]), fmaxf(red[2], red[3]));
    __syncthreads();
    float e = expf(v - m);
    float p = e;
#pragma unroll
    for (int off = 32; off > 0; off >>= 1) p += __shfl_down(p, off);
    if ((tid & 63) == 0) red[tid >> 6] = p;
    __syncthreads();
    float sum = red[0] + red[1] + red[2] + red[3];
    W[s * B_ + tid] = e / sum;
}

// ---------------------------------------------------------------------------
// context[b][h] = sum_s W[s][b]*enc[b,s,h]   grid 256 x 256
// ---------------------------------------------------------------------------
__global__ __launch_bounds__(256) void context_kernel(const float* __restrict__ W,
                                                      const __hip_bfloat16* __restrict__ enc,
                                                      float* __restrict__ out_ctx, // +t*H_ pre-offset
                                                      float* __restrict__ ctxc) {
    __shared__ float lw[S_];
    int b = blockIdx.x, tid = threadIdx.x;
    lw[tid] = W[tid * B_ + b];
    lw[256 + tid] = W[(256 + tid) * B_ + b];
    __syncthreads();
    float acc = 0.f;
    const __hip_bfloat16* ep = enc + (long)b * ENCSTRIDE + tid;
#pragma unroll 8
    for (int s = 0; s < S_; s++) acc += lw[s] * __bfloat162float(ep[s * H_]);
    out_ctx[(long)b * (TLEN_ * H_) + tid] = acc;
    ctxc[b * H_ + tid] = acc;
}

// ---------------------------------------------------------------------------
// cats = [h2|ctx]@ww.T + bw; pred = tanh(cats)@wop.T + bop   grid 256 x 64
// ---------------------------------------------------------------------------
__global__ __launch_bounds__(64) void decout_kernel(const float* __restrict__ h2,
                                                    const float* __restrict__ ctx,
                                                    const float* __restrict__ ww,
                                                    const float* __restrict__ bw,
                                                    const float* __restrict__ wop,
                                                    const float* __restrict__ bop,
                                                    float* __restrict__ out0,  // +t*DI_ pre-offset
                                                    float* __restrict__ pred) {
    int b = blockIdx.x, lane = threadIdx.x;
    float a[DI_] = {0.f, 0.f, 0.f, 0.f, 0.f};
    for (int k = lane; k < 2 * H_; k += 64) {
        float v = (k < H_) ? h2[b * H_ + k] : ctx[b * H_ + k - H_];
#pragma unroll
        for (int m = 0; m < DI_; m++) a[m] += v * ww[m * (2 * H_) + k];
    }
#pragma unroll
    for (int m = 0; m < DI_; m++)
        for (int off = 32; off > 0; off >>= 1) a[m] += __shfl_down(a[m], off);
    if (lane == 0) {
        float t5[DI_];
#pragma unroll
        for (int m = 0; m < DI_; m++) t5[m] = tanhf(a[m] + bw[m]);
#pragma unroll
        for (int m2 = 0; m2 < DI_; m2++) {
            float o = bop[m2];
#pragma unroll
            for (int m = 0; m < DI_; m++) o += t5[m] * wop[m2 * DI_ + m];
            out0[(long)b * (TLEN_ * DI_) + m2] = o;
            pred[b * DI_ + m2] = o;
        }
    }
}

// ---------------------------------------------------------------------------
extern "C" void kernel_launch(void* const* d_in, const int* in_sizes, int n_in,
                              void* d_out, int out_size, void* d_ws, size_t ws_size,
                              hipStream_t stream) {
    const float* srcs   = (const float*)d_in[0];
    const float* wih_e1 = (const float*)d_in[1];
    const float* whh_e1 = (const float*)d_in[2];
    const float* b_e1   = (const float*)d_in[3];
    const float* wih_e2 = (const float*)d_in[4];
    const float* whh_e2 = (const float*)d_in[5];
    const float* b_e2   = (const float*)d_in[6];
    const float* wdi    = (const float*)d_in[7];
    const float* bdi    = (const float*)d_in[8];
    const float* wih_d1 = (const float*)d_in[9];
    const float* whh_d1 = (const float*)d_in[10];
    const float* b_d1   = (const float*)d_in[11];
    const float* wih_d2 = (const float*)d_in[12];
    const float* whh_d2 = (const float*)d_in[13];
    const float* b_d2   = (const float*)d_in[14];
    const float* ww     = (const float*)d_in[15];
    const float* bw     = (const float*)d_in[16];
    const float* wop    = (const float*)d_in[17];
    const float* bop    = (const float*)d_in[18];

    float* ws = (float*)d_ws;
    __hip_bfloat16* ENCBF = (__hip_bfloat16*)d_ws;   // 33.5M bf16 = 16,777,216 float slots
    size_t o = 16777216;
    float4* PKE1 = (float4*)(ws + o); o += 262144;   // whh_e1 packed
    float4* PKX2 = (float4*)(ws + o); o += 262144;   // wih_e2 packed
    float4* PKH2 = (float4*)(ws + o); o += 262144;   // whh_e2 packed
    float4* PKD1 = (float4*)(ws + o); o += 262144;   // whh_d1 packed
    float4* PKD2 = (float4*)(ws + o); o += 262144;   // wih_d2 packed
    float* H1G = ws + o; o += 2 * H1GBUF;            // [2][CHUNK][B][H] h1 chunk ping-pong
    float* C1C = ws + o; o += 65536;                 // layer-1 c carry
    float* H2C = ws + o; o += 65536;                 // layer-2 h carry / decoder h
    float* C2C = ws + o; o += 65536;                 // layer-2 c carry / decoder c
    float* ZB  = ws + o; o += 65536;
    float* H1D = ws + o; o += 65536;
    float* C1D = ws + o; o += 65536;
    float* EN  = ws + o; o += 131072;
    float* WSM = ws + o; o += 131072;
    float* CTX = ws + o; o += 65536;
    float* PRD = ws + o; o += 1280;
    float* WEF = ws + o; o += 5120;
    float* BEF = ws + o; o += 1024;

    float* OUT0 = (float*)d_out;
    float* OUT1 = OUT0 + (size_t)B_ * TLEN_ * DI_;   // context_enc base

    dim3 t256(256);

    init_kernel<<<dim3(256), t256, 0, stream>>>(ZB, PRD);

    pack_kernel<<<dim3(256), t256, 0, stream>>>(whh_e1, PKE1);
    pack_kernel<<<dim3(256), t256, 0, stream>>>(wih_e2, PKX2);
    pack_kernel<<<dim3(256), t256, 0, stream>>>(whh_e2, PKH2);
    pack_kernel<<<dim3(256), t256, 0, stream>>>(whh_d1, PKD1);
    pack_kernel<<<dim3(256), t256, 0, stream>>>(wih_d2, PKD2);
    weff_kernel<<<dim3(4), t256, 0, stream>>>(wih_d1, wdi, bdi, b_d1, WEF, BEF);

    // ---------------- encoder: 17 chunked launches, 1024-thread blocks ----------------
    for (int ci = 0; ci <= NCHUNK; ci++) {
        enc_chunk_kernel<<<dim3(128), dim3(1024), 0, stream>>>(
            ci, srcs, wih_e1, PKE1, PKX2, PKH2, b_e1, b_e2,
            H1G, C1C, H2C, C2C, ENCBF);
    }
    // final states: h_enc = H2C, c_enc = C2C

    // ---------------- decoder: 32 steps ----------------
    for (int t = 0; t < TLEN_; t++) {
        // layer 1: x = pred (K=5 via Weff), h = carry h2, c = carry c2
        dec_cell_kernel<<<dim3(256), t256, 0, stream>>>(
            PRD, DI_, WEF, nullptr, DI_,
            H2C, PKD1, 1, BEF, C2C, C1D, H1D);
        // layer 2: x = h1d (K=256), h=c=0; writes new carry (h2 -> H2C, c2 -> C2C)
        dec_cell_kernel<<<dim3(256), t256, 0, stream>>>(
            H1D, H_, nullptr, PKD2, H_,
            ZB, nullptr, 0, b_d2, ZB, C2C, H2C);
        energies_kernel<<<dim3(16384), t256, 0, stream>>>(H2C, ENCBF, EN);
        softmax_kernel<<<dim3(512), t256, 0, stream>>>(EN, WSM);
        context_kernel<<<dim3(256), t256, 0, stream>>>(WSM, ENCBF, OUT1 + (size_t)t * H_, CTX);
        decout_kernel<<<dim3(256), dim3(64), 0, stream>>>(H2C, CTX, ww, bw, wop, bop,
                                                          OUT0 + (size_t)t * DI_, PRD);
    }
}

// Round 4
// 12665.864 us; speedup vs baseline: 6.1907x; 1.1776x over previous
//
#include <hip/hip_runtime.h>
#include <hip/hip_bf16.h>

#define B_    256
#define S_    512
#define H_    256
#define TLEN_ 32
#define DI_   5
#define ENCSTRIDE 131072   // S_*H_
#define CHUNK 32
#define NCHUNK 16          // S_/CHUNK
#define NB 4               // batches per encoder block

// ---------------------------------------------------------------------------
// init: zero ZB, set decoder inp0 = ones
// ---------------------------------------------------------------------------
__global__ __launch_bounds__(256) void init_kernel(float* ZB, float* PRD) {
    int i = blockIdx.x * 256 + threadIdx.x;      // grid 256 -> 65536
    ZB[i] = 0.f;
    if (i < B_ * DI_) PRD[i] = 1.0f;
}

// ---------------------------------------------------------------------------
// pack a [1024][256] row-major weight into [k4][n] float4 layout:
// out[k4*1024 + n] = {w[n][4k4], w[n][4k4+1], w[n][4k4+2], w[n][4k4+3]}
// ---------------------------------------------------------------------------
__global__ __launch_bounds__(256) void pack_kernel(const float* __restrict__ m,
                                                   float4* __restrict__ out) {
    int idx = blockIdx.x * 256 + threadIdx.x;    // grid 256 -> 65536
    int k4 = idx >> 10, n = idx & 1023;
    out[idx] = ((const float4*)m)[n * 64 + k4];
}

// ---------------------------------------------------------------------------
// Weff[n][m] = sum_k wih_d1[n][k]*wdi[k][m]; beff[n] = b_d1[n] + wih_d1[n]·bdi
// ---------------------------------------------------------------------------
__global__ __launch_bounds__(256) void weff_kernel(const float* __restrict__ wih_d1,
                                                   const float* __restrict__ wdi,
                                                   const float* __restrict__ bdi,
                                                   const float* __restrict__ b_d1,
                                                   float* __restrict__ weff,
                                                   float* __restrict__ beff) {
    int n = blockIdx.x * 256 + threadIdx.x;      // grid 4 -> 1024
    float acc[DI_] = {0.f, 0.f, 0.f, 0.f, 0.f};
    float accb = 0.f;
    for (int k = 0; k < H_; k++) {
        float w = wih_d1[n * H_ + k];
        accb += w * bdi[k];
#pragma unroll
        for (int m = 0; m < DI_; m++) acc[m] += w * wdi[k * DI_ + m];
    }
#pragma unroll
    for (int m = 0; m < DI_; m++) weff[n * DI_ + m] = acc[m];
    beff[n] = b_d1[n] + accb;
}

// ---------------------------------------------------------------------------
// dot-chunk helper: a0..a3 += xv · w{0..3}
// ---------------------------------------------------------------------------
__device__ __forceinline__ void dot4(const float4 xv, const float4 w0, const float4 w1,
                                     const float4 w2, const float4 w3,
                                     float& a0, float& a1, float& a2, float& a3) {
    a0 += xv.x * w0.x + xv.y * w0.y + xv.z * w0.z + xv.w * w0.w;
    a1 += xv.x * w1.x + xv.y * w1.y + xv.z * w1.z + xv.w * w1.w;
    a2 += xv.x * w2.x + xv.y * w2.y + xv.z * w2.z + xv.w * w2.w;
    a3 += xv.x * w3.x + xv.y * w3.y + xv.z * w3.z + xv.w * w3.w;
}

__device__ __forceinline__ void lstm_epilogue(float a0, float a1, float a2, float a3,
                                              float cold, float& cn, float& hn) {
    float ii = 1.f / (1.f + expf(-a0));
    float ff = 1.f / (1.f + expf(-a1));
    float gg = tanhf(a2);
    float oo = 1.f / (1.f + expf(-a3));
    cn = ff * cold + ii * gg;
    hn = oo * tanhf(cn);
}

// ---------------------------------------------------------------------------
// xproj: X2[u][b][n] = sum_k wih_e2[n][k] * e1[u][b][k] for one finished chunk.
// Weight-STATIONARY in registers: thread (nl,kh) holds w[n=nt*64+nl][K-slice
// kh*32..+32) = 8 float4, read ONCE. e1 rows broadcast from LDS (uniform addr
// across the 64 nl-lanes of a wave -> conflict-free broadcast). VALU-bound.
// Grid 256 = 16 n-tiles x 16 row-groups; block 512 threads; rows = (u,b).
// ---------------------------------------------------------------------------
__global__ __launch_bounds__(512) void xproj_kernel(
    const float* __restrict__ h1,      // [CHUNK][B_][H_]
    const float4* __restrict__ wp,     // packed [64][1024] (PKX2)
    float* __restrict__ X2)            // [CHUNK*B_][1024]
{
    __shared__ float es[16][260];      // 16 staged e1 rows
    __shared__ float red[8][16][64];   // [kh][row][nl]
    int tid = threadIdx.x;
    int nt = blockIdx.x & 15, rg = blockIdx.x >> 4;
    int nl = tid & 63, kh = tid >> 6;  // kh in [0,8)
    int n = nt * 64 + nl;

    float4 w[8];
#pragma unroll
    for (int q = 0; q < 8; q++) w[q] = wp[(((kh << 3) + q) << 10) + n];

    for (int rnd = 0; rnd < 32; rnd++) {
        int r0 = rg * 512 + rnd * 16;
        for (int i = tid; i < 1024; i += 512) {
            int rr = i >> 6, c4 = i & 63;
            ((float4*)&es[rr][0])[c4] = ((const float4*)(h1 + (long)(r0 + rr) * H_))[c4];
        }
        __syncthreads();
        float acc[16];
#pragma unroll
        for (int rr = 0; rr < 16; rr++) acc[rr] = 0.f;
#pragma unroll
        for (int q = 0; q < 8; q++) {
            float4 wq = w[q];
#pragma unroll
            for (int rr = 0; rr < 16; rr++) {
                float4 e = ((const float4*)&es[rr][0])[(kh << 3) + q];
                acc[rr] += e.x * wq.x + e.y * wq.y + e.z * wq.z + e.w * wq.w;
            }
        }
#pragma unroll
        for (int rr = 0; rr < 16; rr++) red[kh][rr][nl] = acc[rr];
        __syncthreads();
        for (int rr = kh; rr < 16; rr += 8) {
            float s = 0.f;
#pragma unroll
            for (int kk = 0; kk < 8; kk++) s += red[kk][rr][nl];
            X2[(long)(r0 + rr) * 1024 + n] = s;
        }
        __syncthreads();               // X2/red reads done before next stage
    }
}

// ---------------------------------------------------------------------------
// Chunked encoder v4: 17 launches (ci = 0..16), 128 blocks x 1024 threads.
// Layer-2's input projection is PRECOMPUTED (xproj) -> recurrent step streams
// whh only (1MB/CU/step, the per-CU L1 floor), plus 16KB of X2.
//   accumulate: (kh = tid>>8) owns K-slice [kh*64,+64), j = tid&255
//   reduce:     (bb = tid>>8) owns batch bb, j = tid&255; c in 1 register
// Blocks 0..63: layer-1 chunk ci; blocks 64..127: layer-2 chunk ci-1 using
// X2 written by xproj after the previous launch. Single H1G buffer.
// ---------------------------------------------------------------------------
__global__ __launch_bounds__(1024, 4) void enc_chunk_kernel(
    int ci,
    const float* __restrict__ srcs,
    const float* __restrict__ wih_e1,      // [1024][5] raw
    const float4* __restrict__ whh_e1p,    // packed [64][1024]
    const float4* __restrict__ whh_e2p,
    const float* __restrict__ b_e1,
    const float* __restrict__ b_e2,
    const float* __restrict__ X2,          // [CHUNK*B_][1024] wih_e2 part
    float* __restrict__ H1G,               // [CHUNK][B_][H_] (single buffer)
    float* __restrict__ C1C,               // [B_][H_] layer-1 c carry
    float* __restrict__ H2C,               // [B_][H_] layer-2 h carry (final = h_enc)
    float* __restrict__ C2C,               // [B_][H_] layer-2 c carry (final = c_enc)
    __hip_bfloat16* __restrict__ encbf)    // [b][s][h]
{
    __shared__ float4 red[4][NB][256];     // [kh][bb][j] -> 4 gate partials, 64KB
    __shared__ float hb[NB][260];          // own-layer h (current step)
    __shared__ float sS[NB][160];          // L1 srcs chunk

    int tid = threadIdx.x;
    int kh = tid >> 8;                     // K-slice (accum) == bb (reduce)
    int j  = tid & 255;
    int k40 = kh << 4;                     // 16 k4 iterations per slice

    if (blockIdx.x < 64) {
        // ================= layer 1, chunk ci =================
        if (ci >= NCHUNK) return;
        int b0 = blockIdx.x * NB;
        int ts = ci * CHUNK;

        for (int idx = tid; idx < NB * CHUNK * DI_; idx += 1024) {
            int r = idx / (CHUNK * DI_), off = idx - r * (CHUNK * DI_);
            sS[r][off] = srcs[((long)(b0 + r) * S_ + ts) * DI_ + off];
        }
        // carry-in: last step of previous chunk still in H1G (read before overwrite)
        hb[kh][j] = (ci == 0) ? 0.f : H1G[(CHUNK - 1) * 65536 + (b0 + kh) * H_ + j];
        float creg = (ci == 0) ? 0.f : C1C[(b0 + kh) * H_ + j];
        float bias0 = b_e1[j], bias1 = b_e1[256 + j], bias2 = b_e1[512 + j], bias3 = b_e1[768 + j];
        float wx[4][DI_];
#pragma unroll
        for (int k = 0; k < DI_; k++) {
            wx[0][k] = wih_e1[j * DI_ + k];
            wx[1][k] = wih_e1[(256 + j) * DI_ + k];
            wx[2][k] = wih_e1[(512 + j) * DI_ + k];
            wx[3][k] = wih_e1[(768 + j) * DI_ + k];
        }

        for (int tt = 0; tt < CHUNK; tt++) {
            __syncthreads();               // hb ready; prev red reads done
            float A[NB][4];
#pragma unroll
            for (int bb = 0; bb < NB; bb++) {
                A[bb][0] = 0.f; A[bb][1] = 0.f; A[bb][2] = 0.f; A[bb][3] = 0.f;
            }
            if (kh == 0) {                 // input projection K=5 (wave-uniform branch)
#pragma unroll
                for (int bb = 0; bb < NB; bb++)
#pragma unroll
                    for (int k = 0; k < DI_; k++) {
                        float xv = sS[bb][tt * DI_ + k];
                        A[bb][0] += xv * wx[0][k];
                        A[bb][1] += xv * wx[1][k];
                        A[bb][2] += xv * wx[2][k];
                        A[bb][3] += xv * wx[3][k];
                    }
            }
#pragma unroll 4
            for (int k4 = k40; k4 < k40 + 16; k4++) {
                float4 w0 = whh_e1p[(k4 << 10) + j];
                float4 w1 = whh_e1p[(k4 << 10) + 256 + j];
                float4 w2 = whh_e1p[(k4 << 10) + 512 + j];
                float4 w3 = whh_e1p[(k4 << 10) + 768 + j];
#pragma unroll
                for (int bb = 0; bb < NB; bb++) {
                    float4 h4 = ((const float4*)&hb[bb][0])[k4];
                    dot4(h4, w0, w1, w2, w3, A[bb][0], A[bb][1], A[bb][2], A[bb][3]);
                }
            }
#pragma unroll
            for (int bb = 0; bb < NB; bb++)
                red[kh][bb][j] = make_float4(A[bb][0], A[bb][1], A[bb][2], A[bb][3]);
            __syncthreads();               // red complete; hb reads done
            float a0 = bias0, a1 = bias1, a2 = bias2, a3 = bias3;
#pragma unroll
            for (int kk = 0; kk < 4; kk++) {
                float4 v = red[kk][kh][j];
                a0 += v.x; a1 += v.y; a2 += v.z; a3 += v.w;
            }
            float cn, hn;
            lstm_epilogue(a0, a1, a2, a3, creg, cn, hn);
            creg = cn;
            hb[kh][j] = hn;
            H1G[tt * 65536 + (b0 + kh) * H_ + j] = hn;
        }
        C1C[(b0 + kh) * H_ + j] = creg;
    } else {
        // ================= layer 2, chunk ci-1 =================
        if (ci < 1) return;
        int b0 = (blockIdx.x - 64) * NB;
        int us = (ci - 1) * CHUNK;

        hb[kh][j] = (ci == 1) ? 0.f : H2C[(b0 + kh) * H_ + j];
        float creg = (ci == 1) ? 0.f : C2C[(b0 + kh) * H_ + j];
        float hlast = 0.f;
        float bias0 = b_e2[j], bias1 = b_e2[256 + j], bias2 = b_e2[512 + j], bias3 = b_e2[768 + j];

        for (int tt = 0; tt < CHUNK; tt++) {
            __syncthreads();               // hb ready; prev red reads done
            // prefetch this thread's X2 gate values (used in reduce phase;
            // hidden under the whh accumulate below)
            const float* xrow = X2 + ((long)tt * B_ + b0 + kh) * 1024;
            float x0 = xrow[j], x1 = xrow[256 + j], x2 = xrow[512 + j], x3 = xrow[768 + j];
            float A[NB][4];
#pragma unroll
            for (int bb = 0; bb < NB; bb++) {
                A[bb][0] = 0.f; A[bb][1] = 0.f; A[bb][2] = 0.f; A[bb][3] = 0.f;
            }
#pragma unroll 4
            for (int k4 = k40; k4 < k40 + 16; k4++) {
                float4 w0 = whh_e2p[(k4 << 10) + j];
                float4 w1 = whh_e2p[(k4 << 10) + 256 + j];
                float4 w2 = whh_e2p[(k4 << 10) + 512 + j];
                float4 w3 = whh_e2p[(k4 << 10) + 768 + j];
#pragma unroll
                for (int bb = 0; bb < NB; bb++) {
                    float4 h4 = ((const float4*)&hb[bb][0])[k4];
                    dot4(h4, w0, w1, w2, w3, A[bb][0], A[bb][1], A[bb][2], A[bb][3]);
                }
            }
#pragma unroll
            for (int bb = 0; bb < NB; bb++)
                red[kh][bb][j] = make_float4(A[bb][0], A[bb][1], A[bb][2], A[bb][3]);
            __syncthreads();               // red complete; hb reads done
            float a0 = bias0 + x0, a1 = bias1 + x1, a2 = bias2 + x2, a3 = bias3 + x3;
#pragma unroll
            for (int kk = 0; kk < 4; kk++) {
                float4 v = red[kk][kh][j];
                a0 += v.x; a1 += v.y; a2 += v.z; a3 += v.w;
            }
            float cn, hn;
            lstm_epilogue(a0, a1, a2, a3, creg, cn, hn);
            creg = cn;
            hlast = hn;
            hb[kh][j] = hn;
            encbf[(long)(b0 + kh) * ENCSTRIDE + (us + tt) * H_ + j] = __float2bfloat16(hn);
        }
        H2C[(b0 + kh) * H_ + j] = hlast;
        C2C[(b0 + kh) * H_ + j] = creg;
    }
}

// ---------------------------------------------------------------------------
// Decoder LSTM cell, 16x16 tile, grid 256 x 256.
// kx==5: raw w5 [1024][5]; kx==256: packed wxp. use_whh: add hprev @ whh.
// ---------------------------------------------------------------------------
__global__ __launch_bounds__(256) void dec_cell_kernel(
    const float* __restrict__ x, int xstride,
    const float* __restrict__ w5,
    const float4* __restrict__ wxp, int kx,
    const float* __restrict__ hprev,
    const float4* __restrict__ whhp, int use_whh,
    const float* __restrict__ bias,
    const float* __restrict__ cprev,
    float* __restrict__ cout,
    float* __restrict__ hout)
{
    __shared__ float sA[16][260];
    __shared__ float sB[16][260];
    int tid = threadIdx.x;
    int b0 = ((int)blockIdx.x >> 4) * 16, j0 = ((int)blockIdx.x & 15) * 16;

    if (kx == DI_) {
        if (tid < 16 * DI_) {
            int r = tid / DI_, c = tid % DI_;
            sA[r][c] = x[(b0 + r) * xstride + c];
        }
    } else {
        for (int i = tid; i < 1024; i += 256) {
            int r = i >> 6, c4 = i & 63;
            ((float4*)&sA[r][0])[c4] = ((const float4*)(x + (long)(b0 + r) * xstride))[c4];
        }
    }
    if (use_whh) {
        for (int i = tid; i < 1024; i += 256) {
            int r = i >> 6, c4 = i & 63;
            ((float4*)&sB[r][0])[c4] = ((const float4*)(hprev + (long)(b0 + r) * H_))[c4];
        }
    }
    __syncthreads();

    int bl = tid >> 4, jl = tid & 15, b = b0 + bl, j = j0 + jl;
    float a0 = bias[j], a1 = bias[256 + j], a2 = bias[512 + j], a3 = bias[768 + j];

    if (kx == DI_) {
#pragma unroll
        for (int k = 0; k < DI_; k++) {
            float xv = sA[bl][k];
            a0 += xv * w5[j * DI_ + k];
            a1 += xv * w5[(256 + j) * DI_ + k];
            a2 += xv * w5[(512 + j) * DI_ + k];
            a3 += xv * w5[(768 + j) * DI_ + k];
        }
    } else {
#pragma unroll 4
        for (int k4 = 0; k4 < 64; k4++) {
            float4 xv = ((const float4*)&sA[bl][0])[k4];
            dot4(xv, wxp[(k4 << 10) + j], wxp[(k4 << 10) + 256 + j],
                 wxp[(k4 << 10) + 512 + j], wxp[(k4 << 10) + 768 + j], a0, a1, a2, a3);
        }
    }
    if (use_whh) {
#pragma unroll 4
        for (int k4 = 0; k4 < 64; k4++) {
            float4 xv = ((const float4*)&sB[bl][0])[k4];
            dot4(xv, whhp[(k4 << 10) + j], whhp[(k4 << 10) + 256 + j],
                 whhp[(k4 << 10) + 512 + j], whhp[(k4 << 10) + 768 + j], a0, a1, a2, a3);
        }
    }
    int idx = b * H_ + j;
    float cn, hn;
    lstm_epilogue(a0, a1, a2, a3, cprev[idx], cn, hn);
    cout[idx] = cn;
    hout[idx] = hn;
}

// ---------------------------------------------------------------------------
// energies[s][b] = dot(h2[b,:], enc[b,s,:])   grid 16384 (b x sblk8) x 256
// ---------------------------------------------------------------------------
__global__ __launch_bounds__(256) void energies_kernel(const float* __restrict__ h2,
                                                       const __hip_bfloat16* __restrict__ enc,
                                                       float* __restrict__ E) {
    __shared__ float lh[H_];
    __shared__ float red[4];
    int b = blockIdx.x >> 6;
    int s0 = (int)(blockIdx.x & 63) * 8;
    int tid = threadIdx.x;
    lh[tid] = h2[b * H_ + tid];
    __syncthreads();
    for (int si = 0; si < 8; si++) {
        int s = s0 + si;
        float p = lh[tid] * __bfloat162float(enc[(long)b * ENCSTRIDE + s * H_ + tid]);
#pragma unroll
        for (int off = 32; off > 0; off >>= 1) p += __shfl_down(p, off);
        if ((tid & 63) == 0) red[tid >> 6] = p;
        __syncthreads();
        if (tid == 0) E[s * B_ + b] = red[0] + red[1] + red[2] + red[3];
        __syncthreads();
    }
}

// ---------------------------------------------------------------------------
// softmax over batch (per s): W[s][b]      grid 512 x 256
// ---------------------------------------------------------------------------
__global__ __launch_bounds__(256) void softmax_kernel(const float* __restrict__ E,
                                                      float* __restrict__ W) {
    __shared__ float red[4];
    int s = blockIdx.x, tid = threadIdx.x;
    float v = E[s * B_ + tid];
    float m = v;
#pragma unroll
    for (int off = 32; off > 0; off >>= 1) m = fmaxf(m, __shfl_down(m, off));
    if ((tid & 63) == 0) red[tid >> 6] = m;
    __syncthreads();
    m = fmaxf(fmaxf(red[0], red[1]), fmaxf(red[2], red[3]));
    __syncthreads();
    float e = expf(v - m);
    float p = e;
#pragma unroll
    for (int off = 32; off > 0; off >>= 1) p += __shfl_down(p, off);
    if ((tid & 63) == 0) red[tid >> 6] = p;
    __syncthreads();
    float sum = red[0] + red[1] + red[2] + red[3];
    W[s * B_ + tid] = e / sum;
}

// ---------------------------------------------------------------------------
// context[b][h] = sum_s W[s][b]*enc[b,s,h]   grid 256 x 256
// ---------------------------------------------------------------------------
__global__ __launch_bounds__(256) void context_kernel(const float* __restrict__ W,
                                                      const __hip_bfloat16* __restrict__ enc,
                                                      float* __restrict__ out_ctx, // +t*H_ pre-offset
                                                      float* __restrict__ ctxc) {
    __shared__ float lw[S_];
    int b = blockIdx.x, tid = threadIdx.x;
    lw[tid] = W[tid * B_ + b];
    lw[256 + tid] = W[(256 + tid) * B_ + b];
    __syncthreads();
    float acc = 0.f;
    const __hip_bfloat16* ep = enc + (long)b * ENCSTRIDE + tid;
#pragma unroll 8
    for (int s = 0; s < S_; s++) acc += lw[s] * __bfloat162float(ep[s * H_]);
    out_ctx[(long)b * (TLEN_ * H_) + tid] = acc;
    ctxc[b * H_ + tid] = acc;
}

// ---------------------------------------------------------------------------
// cats = [h2|ctx]@ww.T + bw; pred = tanh(cats)@wop.T + bop   grid 256 x 64
// ---------------------------------------------------------------------------
__global__ __launch_bounds__(64) void decout_kernel(const float* __restrict__ h2,
                                                    const float* __restrict__ ctx,
                                                    const float* __restrict__ ww,
                                                    const float* __restrict__ bw,
                                                    const float* __restrict__ wop,
                                                    const float* __restrict__ bop,
                                                    float* __restrict__ out0,  // +t*DI_ pre-offset
                                                    float* __restrict__ pred) {
    int b = blockIdx.x, lane = threadIdx.x;
    float a[DI_] = {0.f, 0.f, 0.f, 0.f, 0.f};
    for (int k = lane; k < 2 * H_; k += 64) {
        float v = (k < H_) ? h2[b * H_ + k] : ctx[b * H_ + k - H_];
#pragma unroll
        for (int m = 0; m < DI_; m++) a[m] += v * ww[m * (2 * H_) + k];
    }
#pragma unroll
    for (int m = 0; m < DI_; m++)
        for (int off = 32; off > 0; off >>= 1) a[m] += __shfl_down(a[m], off);
    if (lane == 0) {
        float t5[DI_];
#pragma unroll
        for (int m = 0; m < DI_; m++) t5[m] = tanhf(a[m] + bw[m]);
#pragma unroll
        for (int m2 = 0; m2 < DI_; m2++) {
            float o = bop[m2];
#pragma unroll
            for (int m = 0; m < DI_; m++) o += t5[m] * wop[m2 * DI_ + m];
            out0[(long)b * (TLEN_ * DI_) + m2] = o;
            pred[b * DI_ + m2] = o;
        }
    }
}

// ---------------------------------------------------------------------------
extern "C" void kernel_launch(void* const* d_in, const int* in_sizes, int n_in,
                              void* d_out, int out_size, void* d_ws, size_t ws_size,
                              hipStream_t stream) {
    const float* srcs   = (const float*)d_in[0];
    const float* wih_e1 = (const float*)d_in[1];
    const float* whh_e1 = (const float*)d_in[2];
    const float* b_e1   = (const float*)d_in[3];
    const float* wih_e2 = (const float*)d_in[4];
    const float* whh_e2 = (const float*)d_in[5];
    const float* b_e2   = (const float*)d_in[6];
    const float* wdi    = (const float*)d_in[7];
    const float* bdi    = (const float*)d_in[8];
    const float* wih_d1 = (const float*)d_in[9];
    const float* whh_d1 = (const float*)d_in[10];
    const float* b_d1   = (const float*)d_in[11];
    const float* wih_d2 = (const float*)d_in[12];
    const float* whh_d2 = (const float*)d_in[13];
    const float* b_d2   = (const float*)d_in[14];
    const float* ww     = (const float*)d_in[15];
    const float* bw     = (const float*)d_in[16];
    const float* wop    = (const float*)d_in[17];
    const float* bop    = (const float*)d_in[18];

    float* ws = (float*)d_ws;
    __hip_bfloat16* ENCBF = (__hip_bfloat16*)d_ws;   // [256][512][256] bf16 = 16,777,216 float slots
    size_t o = 16777216;
    float4* PKE1 = (float4*)(ws + o); o += 262144;   // whh_e1 packed
    float4* PKX2 = (float4*)(ws + o); o += 262144;   // wih_e2 packed
    float4* PKH2 = (float4*)(ws + o); o += 262144;   // whh_e2 packed
    float4* PKD1 = (float4*)(ws + o); o += 262144;   // whh_d1 packed
    float4* PKD2 = (float4*)(ws + o); o += 262144;   // wih_d2 packed
    float* H1G = ws + o; o += 2097152;               // [CHUNK][B][H] e1 chunk (single)
    float* X2G = ws + o; o += 8388608;               // [CHUNK*B][1024] wih_e2 @ e1
    float* C1C = ws + o; o += 65536;                 // layer-1 c carry
    float* H2C = ws + o; o += 65536;                 // layer-2 h carry / decoder h
    float* C2C = ws + o; o += 65536;                 // layer-2 c carry / decoder c
    float* ZB  = ws + o; o += 65536;
    float* H1D = ws + o; o += 65536;
    float* C1D = ws + o; o += 65536;
    float* EN  = ws + o; o += 131072;
    float* WSM = ws + o; o += 131072;
    float* CTX = ws + o; o += 65536;
    float* PRD = ws + o; o += 1280;
    float* WEF = ws + o; o += 5120;
    float* BEF = ws + o; o += 1024;

    float* OUT0 = (float*)d_out;
    float* OUT1 = OUT0 + (size_t)B_ * TLEN_ * DI_;   // context_enc base

    dim3 t256(256);

    init_kernel<<<dim3(256), t256, 0, stream>>>(ZB, PRD);

    pack_kernel<<<dim3(256), t256, 0, stream>>>(whh_e1, PKE1);
    pack_kernel<<<dim3(256), t256, 0, stream>>>(wih_e2, PKX2);
    pack_kernel<<<dim3(256), t256, 0, stream>>>(whh_e2, PKH2);
    pack_kernel<<<dim3(256), t256, 0, stream>>>(whh_d1, PKD1);
    pack_kernel<<<dim3(256), t256, 0, stream>>>(wih_d2, PKD2);
    weff_kernel<<<dim3(4), t256, 0, stream>>>(wih_d1, wdi, bdi, b_d1, WEF, BEF);

    // ---------------- encoder: 17 chunked launches + 16 xproj GEMMs ----------------
    for (int ci = 0; ci <= NCHUNK; ci++) {
        enc_chunk_kernel<<<dim3(128), dim3(1024), 0, stream>>>(
            ci, srcs, wih_e1, PKE1, PKH2, b_e1, b_e2,
            X2G, H1G, C1C, H2C, C2C, ENCBF);
        if (ci < NCHUNK) {
            // project the chunk L1 just finished: X2(ci) = e1(ci) @ wih_e2^T
            xproj_kernel<<<dim3(256), dim3(512), 0, stream>>>(H1G, PKX2, X2G);
        }
    }
    // final states: h_enc = H2C, c_enc = C2C

    // ---------------- decoder: 32 steps ----------------
    for (int t = 0; t < TLEN_; t++) {
        // layer 1: x = pred (K=5 via Weff), h = carry h2, c = carry c2
        dec_cell_kernel<<<dim3(256), t256, 0, stream>>>(
            PRD, DI_, WEF, nullptr, DI_,
            H2C, PKD1, 1, BEF, C2C, C1D, H1D);
        // layer 2: x = h1d (K=256), h=c=0; writes new carry (h2 -> H2C, c2 -> C2C)
        dec_cell_kernel<<<dim3(256), t256, 0, stream>>>(
            H1D, H_, nullptr, PKD2, H_,
            ZB, nullptr, 0, b_d2, ZB, C2C, H2C);
        energies_kernel<<<dim3(16384), t256, 0, stream>>>(H2C, ENCBF, EN);
        softmax_kernel<<<dim3(512), t256, 0, stream>>>(EN, WSM);
        context_kernel<<<dim3(256), t256, 0, stream>>>(WSM, ENCBF, OUT1 + (size_t)t * H_, CTX);
        decout_kernel<<<dim3(256), dim3(64), 0, stream>>>(H2C, CTX, ww, bw, wop, bop,
                                                          OUT0 + (size_t)t * DI_, PRD);
    }
}

// Round 5
// 11926.551 us; speedup vs baseline: 6.5744x; 1.0620x over previous
//
#include <hip/hip_runtime.h>
#include <hip/hip_bf16.h>

#define B_    256
#define S_    512
#define H_    256
#define TLEN_ 32
#define DI_   5
#define ENCSTRIDE 131072   // S_*H_
#define CHUNK 32
#define NCHUNK 16          // S_/CHUNK
#define NB 4               // batches per encoder block

// ---------------------------------------------------------------------------
// init: zero ZB, set decoder inp0 = ones
// ---------------------------------------------------------------------------
__global__ __launch_bounds__(256) void init_kernel(float* ZB, float* PRD) {
    int i = blockIdx.x * 256 + threadIdx.x;      // grid 256 -> 65536
    ZB[i] = 0.f;
    if (i < B_ * DI_) PRD[i] = 1.0f;
}

// ---------------------------------------------------------------------------
// pack a [1024][256] row-major weight into [k4][n] float4 layout:
// out[k4*1024 + n] = {w[n][4k4], w[n][4k4+1], w[n][4k4+2], w[n][4k4+3]}
// ---------------------------------------------------------------------------
__global__ __launch_bounds__(256) void pack_kernel(const float* __restrict__ m,
                                                   float4* __restrict__ out) {
    int idx = blockIdx.x * 256 + threadIdx.x;    // grid 256 -> 65536
    int k4 = idx >> 10, n = idx & 1023;
    out[idx] = ((const float4*)m)[n * 64 + k4];
}

// ---------------------------------------------------------------------------
// Weff[n][m] = sum_k wih_d1[n][k]*wdi[k][m]; beff[n] = b_d1[n] + wih_d1[n]·bdi
// ---------------------------------------------------------------------------
__global__ __launch_bounds__(256) void weff_kernel(const float* __restrict__ wih_d1,
                                                   const float* __restrict__ wdi,
                                                   const float* __restrict__ bdi,
                                                   const float* __restrict__ b_d1,
                                                   float* __restrict__ weff,
                                                   float* __restrict__ beff) {
    int n = blockIdx.x * 256 + threadIdx.x;      // grid 4 -> 1024
    float acc[DI_] = {0.f, 0.f, 0.f, 0.f, 0.f};
    float accb = 0.f;
    for (int k = 0; k < H_; k++) {
        float w = wih_d1[n * H_ + k];
        accb += w * bdi[k];
#pragma unroll
        for (int m = 0; m < DI_; m++) acc[m] += w * wdi[k * DI_ + m];
    }
#pragma unroll
    for (int m = 0; m < DI_; m++) weff[n * DI_ + m] = acc[m];
    beff[n] = b_d1[n] + accb;
}

// ---------------------------------------------------------------------------
// dot-chunk helper: a0..a3 += xv · w{0..3}
// ---------------------------------------------------------------------------
__device__ __forceinline__ void dot4(const float4 xv, const float4 w0, const float4 w1,
                                     const float4 w2, const float4 w3,
                                     float& a0, float& a1, float& a2, float& a3) {
    a0 += xv.x * w0.x + xv.y * w0.y + xv.z * w0.z + xv.w * w0.w;
    a1 += xv.x * w1.x + xv.y * w1.y + xv.z * w1.z + xv.w * w1.w;
    a2 += xv.x * w2.x + xv.y * w2.y + xv.z * w2.z + xv.w * w2.w;
    a3 += xv.x * w3.x + xv.y * w3.y + xv.z * w3.z + xv.w * w3.w;
}

__device__ __forceinline__ void lstm_epilogue(float a0, float a1, float a2, float a3,
                                              float cold, float& cn, float& hn) {
    float ii = 1.f / (1.f + expf(-a0));
    float ff = 1.f / (1.f + expf(-a1));
    float gg = tanhf(a2);
    float oo = 1.f / (1.f + expf(-a3));
    cn = ff * cold + ii * gg;
    hn = oo * tanhf(cn);
}

// ---------------------------------------------------------------------------
// xproj: X2[u][b][n] = sum_k wih_e2[n][k] * e1[u][b][k] for one finished chunk.
// Weight-stationary in registers; e1 broadcast from LDS. VALU-bound.
// Grid 256 = 16 n-tiles x 16 row-groups; block 512 threads; rows = (u,b).
// ---------------------------------------------------------------------------
__global__ __launch_bounds__(512) void xproj_kernel(
    const float* __restrict__ h1,      // [CHUNK][B_][H_]
    const float4* __restrict__ wp,     // packed [64][1024] (PKX2)
    float* __restrict__ X2)            // [CHUNK*B_][1024]
{
    __shared__ float es[16][260];      // 16 staged e1 rows
    __shared__ float red[8][16][64];   // [kh][row][nl]
    int tid = threadIdx.x;
    int nt = blockIdx.x & 15, rg = blockIdx.x >> 4;
    int nl = tid & 63, kh = tid >> 6;  // kh in [0,8)
    int n = nt * 64 + nl;

    float4 w[8];
#pragma unroll
    for (int q = 0; q < 8; q++) w[q] = wp[(((kh << 3) + q) << 10) + n];

    for (int rnd = 0; rnd < 32; rnd++) {
        int r0 = rg * 512 + rnd * 16;
        for (int i = tid; i < 1024; i += 512) {
            int rr = i >> 6, c4 = i & 63;
            ((float4*)&es[rr][0])[c4] = ((const float4*)(h1 + (long)(r0 + rr) * H_))[c4];
        }
        __syncthreads();
        float acc[16];
#pragma unroll
        for (int rr = 0; rr < 16; rr++) acc[rr] = 0.f;
#pragma unroll
        for (int q = 0; q < 8; q++) {
            float4 wq = w[q];
#pragma unroll
            for (int rr = 0; rr < 16; rr++) {
                float4 e = ((const float4*)&es[rr][0])[(kh << 3) + q];
                acc[rr] += e.x * wq.x + e.y * wq.y + e.z * wq.z + e.w * wq.w;
            }
        }
#pragma unroll
        for (int rr = 0; rr < 16; rr++) red[kh][rr][nl] = acc[rr];
        __syncthreads();
        for (int rr = kh; rr < 16; rr += 8) {
            float s = 0.f;
#pragma unroll
            for (int kk = 0; kk < 8; kk++) s += red[kk][rr][nl];
            X2[(long)(r0 + rr) * 1024 + n] = s;
        }
        __syncthreads();               // X2/red reads done before next stage
    }
}

// ---------------------------------------------------------------------------
// Chunked encoder v4: 17 launches (ci = 0..16), 128 blocks x 1024 threads.
// Layer-2's input projection is PRECOMPUTED (xproj) -> recurrent step streams
// whh only (1MB/CU/step, the per-CU L1 floor), plus 16KB of X2.
// ---------------------------------------------------------------------------
__global__ __launch_bounds__(1024, 4) void enc_chunk_kernel(
    int ci,
    const float* __restrict__ srcs,
    const float* __restrict__ wih_e1,      // [1024][5] raw
    const float4* __restrict__ whh_e1p,    // packed [64][1024]
    const float4* __restrict__ whh_e2p,
    const float* __restrict__ b_e1,
    const float* __restrict__ b_e2,
    const float* __restrict__ X2,          // [CHUNK*B_][1024] wih_e2 part
    float* __restrict__ H1G,               // [CHUNK][B_][H_] (single buffer)
    float* __restrict__ C1C,               // [B_][H_] layer-1 c carry
    float* __restrict__ H2C,               // [B_][H_] layer-2 h carry (final = h_enc)
    float* __restrict__ C2C,               // [B_][H_] layer-2 c carry (final = c_enc)
    __hip_bfloat16* __restrict__ encbf)    // [b][s][h]
{
    __shared__ float4 red[4][NB][256];     // [kh][bb][j] -> 4 gate partials, 64KB
    __shared__ float hb[NB][260];          // own-layer h (current step)
    __shared__ float sS[NB][160];          // L1 srcs chunk

    int tid = threadIdx.x;
    int kh = tid >> 8;                     // K-slice (accum) == bb (reduce)
    int j  = tid & 255;
    int k40 = kh << 4;                     // 16 k4 iterations per slice

    if (blockIdx.x < 64) {
        // ================= layer 1, chunk ci =================
        if (ci >= NCHUNK) return;
        int b0 = blockIdx.x * NB;
        int ts = ci * CHUNK;

        for (int idx = tid; idx < NB * CHUNK * DI_; idx += 1024) {
            int r = idx / (CHUNK * DI_), off = idx - r * (CHUNK * DI_);
            sS[r][off] = srcs[((long)(b0 + r) * S_ + ts) * DI_ + off];
        }
        hb[kh][j] = (ci == 0) ? 0.f : H1G[(CHUNK - 1) * 65536 + (b0 + kh) * H_ + j];
        float creg = (ci == 0) ? 0.f : C1C[(b0 + kh) * H_ + j];
        float bias0 = b_e1[j], bias1 = b_e1[256 + j], bias2 = b_e1[512 + j], bias3 = b_e1[768 + j];
        float wx[4][DI_];
#pragma unroll
        for (int k = 0; k < DI_; k++) {
            wx[0][k] = wih_e1[j * DI_ + k];
            wx[1][k] = wih_e1[(256 + j) * DI_ + k];
            wx[2][k] = wih_e1[(512 + j) * DI_ + k];
            wx[3][k] = wih_e1[(768 + j) * DI_ + k];
        }

        for (int tt = 0; tt < CHUNK; tt++) {
            __syncthreads();               // hb ready; prev red reads done
            float A[NB][4];
#pragma unroll
            for (int bb = 0; bb < NB; bb++) {
                A[bb][0] = 0.f; A[bb][1] = 0.f; A[bb][2] = 0.f; A[bb][3] = 0.f;
            }
            if (kh == 0) {                 // input projection K=5 (wave-uniform branch)
#pragma unroll
                for (int bb = 0; bb < NB; bb++)
#pragma unroll
                    for (int k = 0; k < DI_; k++) {
                        float xv = sS[bb][tt * DI_ + k];
                        A[bb][0] += xv * wx[0][k];
                        A[bb][1] += xv * wx[1][k];
                        A[bb][2] += xv * wx[2][k];
                        A[bb][3] += xv * wx[3][k];
                    }
            }
#pragma unroll 4
            for (int k4 = k40; k4 < k40 + 16; k4++) {
                float4 w0 = whh_e1p[(k4 << 10) + j];
                float4 w1 = whh_e1p[(k4 << 10) + 256 + j];
                float4 w2 = whh_e1p[(k4 << 10) + 512 + j];
                float4 w3 = whh_e1p[(k4 << 10) + 768 + j];
#pragma unroll
                for (int bb = 0; bb < NB; bb++) {
                    float4 h4 = ((const float4*)&hb[bb][0])[k4];
                    dot4(h4, w0, w1, w2, w3, A[bb][0], A[bb][1], A[bb][2], A[bb][3]);
                }
            }
#pragma unroll
            for (int bb = 0; bb < NB; bb++)
                red[kh][bb][j] = make_float4(A[bb][0], A[bb][1], A[bb][2], A[bb][3]);
            __syncthreads();               // red complete; hb reads done
            float a0 = bias0, a1 = bias1, a2 = bias2, a3 = bias3;
#pragma unroll
            for (int kk = 0; kk < 4; kk++) {
                float4 v = red[kk][kh][j];
                a0 += v.x; a1 += v.y; a2 += v.z; a3 += v.w;
            }
            float cn, hn;
            lstm_epilogue(a0, a1, a2, a3, creg, cn, hn);
            creg = cn;
            hb[kh][j] = hn;
            H1G[tt * 65536 + (b0 + kh) * H_ + j] = hn;
        }
        C1C[(b0 + kh) * H_ + j] = creg;
    } else {
        // ================= layer 2, chunk ci-1 =================
        if (ci < 1) return;
        int b0 = (blockIdx.x - 64) * NB;
        int us = (ci - 1) * CHUNK;

        hb[kh][j] = (ci == 1) ? 0.f : H2C[(b0 + kh) * H_ + j];
        float creg = (ci == 1) ? 0.f : C2C[(b0 + kh) * H_ + j];
        float hlast = 0.f;
        float bias0 = b_e2[j], bias1 = b_e2[256 + j], bias2 = b_e2[512 + j], bias3 = b_e2[768 + j];

        for (int tt = 0; tt < CHUNK; tt++) {
            __syncthreads();               // hb ready; prev red reads done
            const float* xrow = X2 + ((long)tt * B_ + b0 + kh) * 1024;
            float x0 = xrow[j], x1 = xrow[256 + j], x2 = xrow[512 + j], x3 = xrow[768 + j];
            float A[NB][4];
#pragma unroll
            for (int bb = 0; bb < NB; bb++) {
                A[bb][0] = 0.f; A[bb][1] = 0.f; A[bb][2] = 0.f; A[bb][3] = 0.f;
            }
#pragma unroll 4
            for (int k4 = k40; k4 < k40 + 16; k4++) {
                float4 w0 = whh_e2p[(k4 << 10) + j];
                float4 w1 = whh_e2p[(k4 << 10) + 256 + j];
                float4 w2 = whh_e2p[(k4 << 10) + 512 + j];
                float4 w3 = whh_e2p[(k4 << 10) + 768 + j];
#pragma unroll
                for (int bb = 0; bb < NB; bb++) {
                    float4 h4 = ((const float4*)&hb[bb][0])[k4];
                    dot4(h4, w0, w1, w2, w3, A[bb][0], A[bb][1], A[bb][2], A[bb][3]);
                }
            }
#pragma unroll
            for (int bb = 0; bb < NB; bb++)
                red[kh][bb][j] = make_float4(A[bb][0], A[bb][1], A[bb][2], A[bb][3]);
            __syncthreads();               // red complete; hb reads done
            float a0 = bias0 + x0, a1 = bias1 + x1, a2 = bias2 + x2, a3 = bias3 + x3;
#pragma unroll
            for (int kk = 0; kk < 4; kk++) {
                float4 v = red[kk][kh][j];
                a0 += v.x; a1 += v.y; a2 += v.z; a3 += v.w;
            }
            float cn, hn;
            lstm_epilogue(a0, a1, a2, a3, creg, cn, hn);
            creg = cn;
            hlast = hn;
            hb[kh][j] = hn;
            encbf[(long)(b0 + kh) * ENCSTRIDE + (us + tt) * H_ + j] = __float2bfloat16(hn);
        }
        H2C[(b0 + kh) * H_ + j] = hlast;
        C2C[(b0 + kh) * H_ + j] = creg;
    }
}

// ---------------------------------------------------------------------------
// Fused decoder step: cell1 + cell2 + energies in ONE launch.
// 128 blocks x 1024 threads; block owns 2 batches, all 1024 gates (j = tid).
// cell2 has NO h-recurrence (re-zeroed every step) -> fully block-local.
//   phase A: gates1 = Weff@pred + BEF + whh_d1@h2prev -> epilogue(c2prev) -> h1 (LDS)
//   phase B: gates2 = wih_d2@h1 + b_d2 -> epilogue(0) -> h2 (LDS + H2C), c2 (C2C)
//   phase C: E[s][b] = h2[b]·enc[b,s,:]  (16 waves: wave = (bb, s mod 8))
// ---------------------------------------------------------------------------
__global__ __launch_bounds__(1024) void dec_step_kernel(
    const float* __restrict__ PRD,
    const float* __restrict__ WEF,       // [1024][5]
    const float* __restrict__ BEF,       // [1024]
    const float4* __restrict__ whhd1p,   // packed [64][1024]
    const float4* __restrict__ wihd2p,   // packed [64][1024]
    const float* __restrict__ b_d2,
    float* __restrict__ H2C,             // in: h2prev, out: h2new (own rows only)
    float* __restrict__ C2C,             // in: c2prev, out: c2new (own rows only)
    const __hip_bfloat16* __restrict__ enc,
    float* __restrict__ E)               // [S_][B_]
{
    __shared__ float h2s[2][260];        // h2prev
    __shared__ float h1s[2][260];
    __shared__ float h2n[2][260];        // h2 new
    __shared__ float g[2][1024];         // gate accum staging
    __shared__ float prd[2][8];
    int tid = threadIdx.x;
    int j = tid;
    int b0 = blockIdx.x * 2;

    if (tid < 512) h2s[tid >> 8][tid & 255] = H2C[(b0 + (tid >> 8)) * H_ + (tid & 255)];
    if (tid < 2 * DI_) prd[tid / DI_][tid % DI_] = PRD[(b0 + tid / DI_) * DI_ + tid % DI_];
    __syncthreads();

    // ---- phase A: cell1 gates ----
    {
        float wef[DI_];
#pragma unroll
        for (int m = 0; m < DI_; m++) wef[m] = WEF[j * DI_ + m];
        float be = BEF[j];
        float a[2];
#pragma unroll
        for (int bb = 0; bb < 2; bb++) {
            a[bb] = be;
#pragma unroll
            for (int m = 0; m < DI_; m++) a[bb] += wef[m] * prd[bb][m];
        }
#pragma unroll 4
        for (int k4 = 0; k4 < 64; k4++) {
            float4 w = whhd1p[(k4 << 10) + j];
#pragma unroll
            for (int bb = 0; bb < 2; bb++) {
                float4 h4 = ((const float4*)&h2s[bb][0])[k4];
                a[bb] += h4.x * w.x + h4.y * w.y + h4.z * w.z + h4.w * w.w;
            }
        }
        g[0][j] = a[0]; g[1][j] = a[1];
    }
    __syncthreads();
    if (tid < 512) {
        int bb = tid >> 8, n = tid & 255;
        float cn, hn;
        lstm_epilogue(g[bb][n], g[bb][256 + n], g[bb][512 + n], g[bb][768 + n],
                      C2C[(b0 + bb) * H_ + n], cn, hn);
        h1s[bb][n] = hn;                 // c1 is not carried
    }
    __syncthreads();

    // ---- phase B: cell2 gates (h=c=0, no whh) ----
    {
        float b2 = b_d2[j];
        float a[2] = {b2, b2};
#pragma unroll 4
        for (int k4 = 0; k4 < 64; k4++) {
            float4 w = wihd2p[(k4 << 10) + j];
#pragma unroll
            for (int bb = 0; bb < 2; bb++) {
                float4 h4 = ((const float4*)&h1s[bb][0])[k4];
                a[bb] += h4.x * w.x + h4.y * w.y + h4.z * w.z + h4.w * w.w;
            }
        }
        g[0][j] = a[0]; g[1][j] = a[1];
    }
    __syncthreads();
    if (tid < 512) {
        int bb = tid >> 8, n = tid & 255;
        float cn, hn;
        lstm_epilogue(g[bb][n], g[bb][256 + n], g[bb][512 + n], g[bb][768 + n],
                      0.f, cn, hn);
        C2C[(b0 + bb) * H_ + n] = cn;
        H2C[(b0 + bb) * H_ + n] = hn;
        h2n[bb][n] = hn;
    }
    __syncthreads();

    // ---- phase C: energies ----
    {
        int wv = tid >> 6, lane = tid & 63;
        int bb = wv >> 3, ws = wv & 7;
        const __hip_bfloat16* ep = enc + (long)(b0 + bb) * ENCSTRIDE;
        float h0 = h2n[bb][lane], h1v = h2n[bb][64 + lane];
        float h2v = h2n[bb][128 + lane], h3v = h2n[bb][192 + lane];
        for (int si = 0; si < 64; si++) {
            int s = ws + (si << 3);
            const __hip_bfloat16* er = ep + s * H_;
            float p = h0 * __bfloat162float(er[lane]) +
                      h1v * __bfloat162float(er[64 + lane]) +
                      h2v * __bfloat162float(er[128 + lane]) +
                      h3v * __bfloat162float(er[192 + lane]);
#pragma unroll
            for (int off = 32; off > 0; off >>= 1) p += __shfl_down(p, off);
            if (lane == 0) E[s * B_ + b0 + bb] = p;
        }
    }
}

// ---------------------------------------------------------------------------
// softmax over batch (per s): W[s][b]      grid 512 x 256
// ---------------------------------------------------------------------------
__global__ __launch_bounds__(256) void softmax_kernel(const float* __restrict__ E,
                                                      float* __restrict__ W) {
    __shared__ float red[4];
    int s = blockIdx.x, tid = threadIdx.x;
    float v = E[s * B_ + tid];
    float m = v;
#pragma unroll
    for (int off = 32; off > 0; off >>= 1) m = fmaxf(m, __shfl_down(m, off));
    if ((tid & 63) == 0) red[tid >> 6] = m;
    __syncthreads();
    m = fmaxf(fmaxf(red[0], red[1]), fmaxf(red[2], red[3]));
    __syncthreads();
    float e = expf(v - m);
    float p = e;
#pragma unroll
    for (int off = 32; off > 0; off >>= 1) p += __shfl_down(p, off);
    if ((tid & 63) == 0) red[tid >> 6] = p;
    __syncthreads();
    float sum = red[0] + red[1] + red[2] + red[3];
    W[s * B_ + tid] = e / sum;
}

// ---------------------------------------------------------------------------
// context + decout fused: block b computes ctx[b][:] (thread = h), then the
// 2H->DI_ and DI_->DI_ matvecs on wave 0 (identical order to old decout).
// ---------------------------------------------------------------------------
__global__ __launch_bounds__(256) void ctx_out_kernel(
    const float* __restrict__ W,
    const __hip_bfloat16* __restrict__ enc,
    const float* __restrict__ h2,
    const float* __restrict__ ww, const float* __restrict__ bw,
    const float* __restrict__ wop, const float* __restrict__ bop,
    float* __restrict__ out_ctx,   // OUT1 + t*H_ pre-offset
    float* __restrict__ out0,      // OUT0 + t*DI_ pre-offset
    float* __restrict__ pred)
{
    __shared__ float lw[S_];
    __shared__ float hc[512];      // [h2 | ctx]
    int b = blockIdx.x, tid = threadIdx.x;
    lw[tid] = W[tid * B_ + b];
    lw[256 + tid] = W[(256 + tid) * B_ + b];
    hc[tid] = h2[b * H_ + tid];
    __syncthreads();
    float acc = 0.f;
    const __hip_bfloat16* ep = enc + (long)b * ENCSTRIDE + tid;
#pragma unroll 8
    for (int s = 0; s < S_; s++) acc += lw[s] * __bfloat162float(ep[s * H_]);
    out_ctx[(long)b * (TLEN_ * H_) + tid] = acc;
    hc[256 + tid] = acc;
    __syncthreads();
    if (tid < 64) {
        float a[DI_] = {0.f, 0.f, 0.f, 0.f, 0.f};
        for (int k = tid; k < 2 * H_; k += 64) {
            float v = hc[k];
#pragma unroll
            for (int m = 0; m < DI_; m++) a[m] += v * ww[m * (2 * H_) + k];
        }
#pragma unroll
        for (int m = 0; m < DI_; m++)
            for (int off = 32; off > 0; off >>= 1) a[m] += __shfl_down(a[m], off);
        if (tid == 0) {
            float t5[DI_];
#pragma unroll
            for (int m = 0; m < DI_; m++) t5[m] = tanhf(a[m] + bw[m]);
#pragma unroll
            for (int m2 = 0; m2 < DI_; m2++) {
                float o = bop[m2];
#pragma unroll
                for (int m = 0; m < DI_; m++) o += t5[m] * wop[m2 * DI_ + m];
                out0[(long)b * (TLEN_ * DI_) + m2] = o;
                pred[b * DI_ + m2] = o;
            }
        }
    }
}

// ---------------------------------------------------------------------------
extern "C" void kernel_launch(void* const* d_in, const int* in_sizes, int n_in,
                              void* d_out, int out_size, void* d_ws, size_t ws_size,
                              hipStream_t stream) {
    const float* srcs   = (const float*)d_in[0];
    const float* wih_e1 = (const float*)d_in[1];
    const float* whh_e1 = (const float*)d_in[2];
    const float* b_e1   = (const float*)d_in[3];
    const float* wih_e2 = (const float*)d_in[4];
    const float* whh_e2 = (const float*)d_in[5];
    const float* b_e2   = (const float*)d_in[6];
    const float* wdi    = (const float*)d_in[7];
    const float* bdi    = (const float*)d_in[8];
    const float* wih_d1 = (const float*)d_in[9];
    const float* whh_d1 = (const float*)d_in[10];
    const float* b_d1   = (const float*)d_in[11];
    const float* wih_d2 = (const float*)d_in[12];
    const float* whh_d2 = (const float*)d_in[13];
    const float* b_d2   = (const float*)d_in[14];
    const float* ww     = (const float*)d_in[15];
    const float* bw     = (const float*)d_in[16];
    const float* wop    = (const float*)d_in[17];
    const float* bop    = (const float*)d_in[18];

    float* ws = (float*)d_ws;
    __hip_bfloat16* ENCBF = (__hip_bfloat16*)d_ws;   // [256][512][256] bf16 = 16,777,216 float slots
    size_t o = 16777216;
    float4* PKE1 = (float4*)(ws + o); o += 262144;   // whh_e1 packed
    float4* PKX2 = (float4*)(ws + o); o += 262144;   // wih_e2 packed
    float4* PKH2 = (float4*)(ws + o); o += 262144;   // whh_e2 packed
    float4* PKD1 = (float4*)(ws + o); o += 262144;   // whh_d1 packed
    float4* PKD2 = (float4*)(ws + o); o += 262144;   // wih_d2 packed
    float* H1G = ws + o; o += 2097152;               // [CHUNK][B][H] e1 chunk (single)
    float* X2G = ws + o; o += 8388608;               // [CHUNK*B][1024] wih_e2 @ e1
    float* C1C = ws + o; o += 65536;                 // layer-1 c carry
    float* H2C = ws + o; o += 65536;                 // layer-2 h carry / decoder h
    float* C2C = ws + o; o += 65536;                 // layer-2 c carry / decoder c
    float* ZB  = ws + o; o += 65536;
    float* EN  = ws + o; o += 131072;
    float* WSM = ws + o; o += 131072;
    float* PRD = ws + o; o += 1280;
    float* WEF = ws + o; o += 5120;
    float* BEF = ws + o; o += 1024;

    float* OUT0 = (float*)d_out;
    float* OUT1 = OUT0 + (size_t)B_ * TLEN_ * DI_;   // context_enc base

    dim3 t256(256);

    init_kernel<<<dim3(256), t256, 0, stream>>>(ZB, PRD);

    pack_kernel<<<dim3(256), t256, 0, stream>>>(whh_e1, PKE1);
    pack_kernel<<<dim3(256), t256, 0, stream>>>(wih_e2, PKX2);
    pack_kernel<<<dim3(256), t256, 0, stream>>>(whh_e2, PKH2);
    pack_kernel<<<dim3(256), t256, 0, stream>>>(whh_d1, PKD1);
    pack_kernel<<<dim3(256), t256, 0, stream>>>(wih_d2, PKD2);
    weff_kernel<<<dim3(4), t256, 0, stream>>>(wih_d1, wdi, bdi, b_d1, WEF, BEF);

    // ---------------- encoder: 17 chunked launches + 16 xproj GEMMs ----------------
    for (int ci = 0; ci <= NCHUNK; ci++) {
        enc_chunk_kernel<<<dim3(128), dim3(1024), 0, stream>>>(
            ci, srcs, wih_e1, PKE1, PKH2, b_e1, b_e2,
            X2G, H1G, C1C, H2C, C2C, ENCBF);
        if (ci < NCHUNK) {
            xproj_kernel<<<dim3(256), dim3(512), 0, stream>>>(H1G, PKX2, X2G);
        }
    }
    // final states: h_enc = H2C, c_enc = C2C

    // ---------------- decoder: 32 steps x 3 launches ----------------
    for (int t = 0; t < TLEN_; t++) {
        dec_step_kernel<<<dim3(128), dim3(1024), 0, stream>>>(
            PRD, WEF, BEF, PKD1, PKD2, b_d2, H2C, C2C, ENCBF, EN);
        softmax_kernel<<<dim3(512), t256, 0, stream>>>(EN, WSM);
        ctx_out_kernel<<<dim3(256), t256, 0, stream>>>(
            WSM, ENCBF, H2C, ww, bw, wop, bop,
            OUT1 + (size_t)t * H_, OUT0 + (size_t)t * DI_, PRD);
    }
}